// Round 10
// baseline (945.587 us; speedup 1.0000x reference)
//
#include <hip/hip_runtime.h>
#include <hip/hip_bf16.h>
#include <math.h>
#include <stdio.h>

static constexpr int   kN  = 800;    // nodes
static constexpr int   kF  = 111;    // input features
static constexpr int   kE  = 32;     // embed dim
static constexpr int   kH  = 200;    // hidden
static constexpr int   kNC = 15;     // classes
static constexpr int   kNE = 8000;   // edges per type
static constexpr long  kNN = (long)kN*kN;   // 640000
static constexpr long  kNH = (long)kN*kH;   // 160000
static constexpr float kAl  = 0.5f;  // ALPHA
static constexpr float kEps = 1e-5f;
static constexpr int   kGB  = (int)((kNH+255)/256);  // gather blocks = 625
static constexpr int   kDB  = 50;    // trsm diagonal block size
static constexpr int   kCH  = 50;    // scan chunk size (nodes)
static constexpr int   kNCHK= kN/kCH; // 16 chunks

typedef unsigned short u16;
typedef __attribute__((ext_vector_type(8))) short short8;
typedef __attribute__((ext_vector_type(4))) float f32x4;

__device__ __forceinline__ u16 f2bf(float v){
  __hip_bfloat16 b = __float2bfloat16(v);
  return *reinterpret_cast<u16*>(&b);
}
__device__ __forceinline__ float bf2f(u16 h){
  unsigned int u = ((unsigned int)h) << 16;
  float f; __builtin_memcpy(&f, &u, 4);
  return f;
}

enum { EPI_NONE=0, EPI_BIAS=1, EPI_SCALE=4, EPI_ACC=6 };

// ---------------------------------------------------------------- fp32 GEMM (software-pipelined, float4 loads)
// LNA: apply graph-LN to A on load: a' = (a - mu)*(rs*lnw[k]) + lnw[kH+k];
// stats read directly from lnst (2 doubles: sum, sumsq — atomically accumulated upstream).
template<bool TRIUA, bool TRIUB, int EPI, bool LNA>
__global__ __launch_bounds__(256)
void gemm_kernel(const float* __restrict__ A, int lda,
                 const float* __restrict__ B, int ldb,
                 float* __restrict__ C, int ldc,
                 int M, int Ncl, int K,
                 long sA, long sB, long sC, float scale,
                 const float* __restrict__ bias, int kstep,
                 const double* __restrict__ scalp,
                 const float* __restrict__ lnw,
                 const double* __restrict__ lnst)
{
  constexpr int TM=64, TN=64, TK=16;
  A += (long)blockIdx.z * sA;
  B += (long)blockIdx.z * sB;
  C += (long)blockIdx.z * sC;
  __shared__ __align__(16) float As[TK][TM+4];
  __shared__ __align__(16) float Bs[TK][TN+4];
  const int tid = threadIdx.x;
  const int tn4 = (tid & 15)*4, tm4 = (tid >> 4)*4;
  const int m0 = blockIdx.x * TM, n0 = blockIdx.y * TN;
  float acc[4][4] = {};
  float mu = 0.f, rsf = 1.f;
  if (LNA){
    double m = lnst[0]/(double)kNH;
    double var = lnst[1]/(double)kNH - m*m;
    mu = (float)m;
    rsf = rsqrtf((float)var + kEps);
  }
  const int kbase = kstep ? (int)blockIdx.z * kstep : 0;
  int k0 = TRIUA ? max(m0 - kbase, 0) : 0;
  int kEnd = TRIUB ? min(K, n0 + TN - kbase) : K;
  const bool skip = (k0 >= kEnd);
  if (skip && EPI == EPI_ACC) return;
  if (!skip) {
    // thread->element maps: A: row am, cols ak..ak+3 ; B: row bk, cols bn..bn+3
    const int am = tid >> 2, ak = (tid & 3) * 4;
    const int bk = tid >> 4, bn = (tid & 15) * 4;
    const bool avec = ((lda & 3) == 0);
    const bool bvec = ((ldb & 3) == 0);
    float4 av, bv;
    auto loadT = [&](int kk0){
      av = make_float4(0.f,0.f,0.f,0.f);
      bv = make_float4(0.f,0.f,0.f,0.f);
      {
        int gm = m0 + am, gk = kk0 + ak;
        if (gm < M && gk < K){
          if (avec && (gk + 4 <= K)){
            av = *(const float4*)(A + (long)gm*lda + gk);
            if (LNA){
              av.x = (av.x - mu)*(rsf*lnw[gk+0]) + lnw[kH+gk+0];
              av.y = (av.y - mu)*(rsf*lnw[gk+1]) + lnw[kH+gk+1];
              av.z = (av.z - mu)*(rsf*lnw[gk+2]) + lnw[kH+gk+2];
              av.w = (av.w - mu)*(rsf*lnw[gk+3]) + lnw[kH+gk+3];
            }
          } else {
            float tmp[4] = {0.f,0.f,0.f,0.f};
            #pragma unroll
            for (int j=0;j<4;++j){
              int k2 = gk + j;
              if (k2 < K){
                float v = A[(long)gm*lda + k2];
                if (LNA) v = (v - mu)*(rsf*lnw[k2]) + lnw[kH + k2];
                tmp[j] = v;
              }
            }
            av = make_float4(tmp[0],tmp[1],tmp[2],tmp[3]);
          }
        }
      }
      {
        int gk = kk0 + bk, gn = n0 + bn;
        if (gk < K && gn < Ncl){
          if (bvec && (gn + 4 <= Ncl)){
            bv = *(const float4*)(B + (long)gk*ldb + gn);
          } else {
            float tmp[4] = {0.f,0.f,0.f,0.f};
            #pragma unroll
            for (int j=0;j<4;++j) if (gn+j < Ncl) tmp[j] = B[(long)gk*ldb + gn + j];
            bv = make_float4(tmp[0],tmp[1],tmp[2],tmp[3]);
          }
        }
      }
    };
    auto storeT = [&](){
      As[ak+0][am] = av.x;
      As[ak+1][am] = av.y;
      As[ak+2][am] = av.z;
      As[ak+3][am] = av.w;
      *(float4*)&Bs[bk][bn] = bv;
    };
    loadT(k0);
    for (;;){
      __syncthreads();
      storeT();
      __syncthreads();
      int kn = k0 + TK;
      bool more = kn < kEnd;
      if (more) loadT(kn);
      #pragma unroll
      for (int kk=0; kk<TK; ++kk) {
        float a[4], b[4];
        #pragma unroll
        for (int u=0;u<4;++u){ a[u]=As[kk][tm4+u]; b[u]=Bs[kk][tn4+u]; }
        #pragma unroll
        for (int i=0;i<4;++i)
          #pragma unroll
          for (int j=0;j<4;++j)
            acc[i][j] = fmaf(a[i], b[j], acc[i][j]);
      }
      if (!more) break;
      k0 = kn;
    }
  }
  float sc = scale;
  if (EPI == EPI_ACC && scalp) sc *= (float)sqrt(sqrt(scalp[0]));
  #pragma unroll
  for (int i=0;i<4;++i) {
    int gm = m0 + tm4 + i;
    if (gm >= M) continue;
    #pragma unroll
    for (int j=0;j<4;++j) {
      int gn = n0 + tn4 + j;
      if (gn >= Ncl) continue;
      float v = acc[i][j];
      long off = (long)gm*ldc + gn;
      if (EPI == EPI_BIAS)       C[off] = v + bias[gn];
      else if (EPI == EPI_SCALE) C[off] = scale*v;
      else if (EPI == EPI_ACC)   unsafeAtomicAdd(&C[off], sc*v);
      else                       C[off] = v;
    }
  }
}

template<bool TRIUA, bool TRIUB, int EPI, bool LNA = false>
static inline void launch_gemm(hipStream_t st,
                               const float* A, int lda, const float* B, int ldb,
                               float* C, int ldc, int M, int Ncl, int K, int batch,
                               long sA, long sB, long sC, float scale,
                               const float* bias = nullptr, int kstep = 0,
                               const double* scalp = nullptr,
                               const float* lnw = nullptr,
                               const double* lnst = nullptr)
{
  dim3 grid((M+63)/64, (Ncl+63)/64, batch);
  gemm_kernel<TRIUA,TRIUB,EPI,LNA><<<grid, 256, 0, st>>>(
      A,lda,B,ldb,C,ldc,M,Ncl,K,sA,sB,sC,scale,bias,kstep,scalp,lnw,lnst);
}

// ---------------------------------------------------------------- split-bf16 MFMA GEMM (powers, pipelined)
__global__ __launch_bounds__(256)
void bgemm2_kernel(const u16* __restrict__ Ah, const u16* __restrict__ Al,
                   const u16* __restrict__ Bh, const u16* __restrict__ Bl,
                   float* __restrict__ C, float* __restrict__ C2,
                   u16* __restrict__ Oh, u16* __restrict__ Ol,
                   float p0, float p1)
{
  constexpr int TM=64, TN=64, BK=32;
  __shared__ u16 Ash[TM][40], Asl[TM][40], Bsh[TN][40], Bsl[TN][40];
  const int tid = threadIdx.x;
  const int m0 = blockIdx.x*TM, n0 = blockIdx.y*TN;
  const int w = tid>>6, lane = tid&63;
  const int wm = (w&1)*32, wn = (w>>1)*32;
  const int quad = lane>>4, lm = lane&15;
  f32x4 acc00={}, acc01={}, acc10={}, acc11={};
  const bool skip = (m0 > n0 + TN - 1);
  int k0 = m0;
  const int kEnd = min(kN, n0+TN);
  const int ar = tid>>2, ac = (tid&3)*8;
  if (!skip){
    uint4 avh, avl, bvh, bvl;
    auto loadT = [&](int kk0){
      avh = {0,0,0,0}; avl = {0,0,0,0}; bvh = {0,0,0,0}; bvl = {0,0,0,0};
      int gk = kk0 + ac;
      if (m0+ar < kN && gk < kN){
        avh = *(const uint4*)(Ah + (long)(m0+ar)*kN + gk);
        avl = *(const uint4*)(Al + (long)(m0+ar)*kN + gk);
      }
      if (n0+ar < kN && gk < kN){
        bvh = *(const uint4*)(Bh + (long)(n0+ar)*kN + gk);
        bvl = *(const uint4*)(Bl + (long)(n0+ar)*kN + gk);
      }
    };
    loadT(k0);
    for (;;){
      __syncthreads();
      *(uint4*)&Ash[ar][ac] = avh; *(uint4*)&Asl[ar][ac] = avl;
      *(uint4*)&Bsh[ar][ac] = bvh; *(uint4*)&Bsl[ar][ac] = bvl;
      __syncthreads();
      int kn = k0 + BK;
      bool more = kn < kEnd;
      if (more) loadT(kn);
      short8 a0h = *(const short8*)&Ash[wm+lm][quad*8];
      short8 a1h = *(const short8*)&Ash[wm+16+lm][quad*8];
      short8 a0l = *(const short8*)&Asl[wm+lm][quad*8];
      short8 a1l = *(const short8*)&Asl[wm+16+lm][quad*8];
      short8 b0h = *(const short8*)&Bsh[wn+lm][quad*8];
      short8 b1h = *(const short8*)&Bsh[wn+16+lm][quad*8];
      short8 b0l = *(const short8*)&Bsl[wn+lm][quad*8];
      short8 b1l = *(const short8*)&Bsl[wn+16+lm][quad*8];
      acc00 = __builtin_amdgcn_mfma_f32_16x16x32_bf16(a0h,b0h,acc00,0,0,0);
      acc00 = __builtin_amdgcn_mfma_f32_16x16x32_bf16(a0h,b0l,acc00,0,0,0);
      acc00 = __builtin_amdgcn_mfma_f32_16x16x32_bf16(a0l,b0h,acc00,0,0,0);
      acc01 = __builtin_amdgcn_mfma_f32_16x16x32_bf16(a0h,b1h,acc01,0,0,0);
      acc01 = __builtin_amdgcn_mfma_f32_16x16x32_bf16(a0h,b1l,acc01,0,0,0);
      acc01 = __builtin_amdgcn_mfma_f32_16x16x32_bf16(a0l,b1h,acc01,0,0,0);
      acc10 = __builtin_amdgcn_mfma_f32_16x16x32_bf16(a1h,b0h,acc10,0,0,0);
      acc10 = __builtin_amdgcn_mfma_f32_16x16x32_bf16(a1h,b0l,acc10,0,0,0);
      acc10 = __builtin_amdgcn_mfma_f32_16x16x32_bf16(a1l,b0h,acc10,0,0,0);
      acc11 = __builtin_amdgcn_mfma_f32_16x16x32_bf16(a1h,b1h,acc11,0,0,0);
      acc11 = __builtin_amdgcn_mfma_f32_16x16x32_bf16(a1h,b1l,acc11,0,0,0);
      acc11 = __builtin_amdgcn_mfma_f32_16x16x32_bf16(a1l,b1h,acc11,0,0,0);
      if (!more) break;
      k0 = kn;
    }
  }
  f32x4 accs[2][2] = {{acc00, acc01},{acc10, acc11}};
  #pragma unroll
  for (int ti=0; ti<2; ++ti){
    #pragma unroll
    for (int tj=0; tj<2; ++tj){
      #pragma unroll
      for (int r=0; r<4; ++r){
        int gm = m0 + wm + ti*16 + quad*4 + r;
        int gn = n0 + wn + tj*16 + lm;
        if (gm >= kN || gn >= kN) continue;
        float v = accs[ti][tj][r];
        long off = (long)gm*kN + gn;
        C[off]  += p0*v;
        C2[off] += p1*v;
        if (Oh){
          u16 h = f2bf(v);
          Oh[off] = h;
          Ol[off] = f2bf(v - bf2f(h));
        }
      }
    }
  }
}

// ---------------------------------------------------------------- pairwise S via MFMA
// prep: per node n, z = LN(tnh), write hi/lo of (w.*z) and z, and a[n]=sum w z^2
// also zeroes *frobz (consumed later by bgemm_pair's atomics; stream-ordered)
__global__ __launch_bounds__(256)
void ln_pair_prep_kernel(const float* __restrict__ tnh, const double* __restrict__ lnst,
                         const float* __restrict__ ln, const float* __restrict__ linW,
                         u16* __restrict__ zwh, u16* __restrict__ zwl,
                         u16* __restrict__ zzh, u16* __restrict__ zzl,
                         float* __restrict__ avec, double* __restrict__ frobz)
{
  __shared__ float ared[256];
  const int n = blockIdx.x, t = threadIdx.x;
  if (t == 0) *frobz = 0.0;   // benign same-value race across blocks
  double m = lnst[0]/(double)kNH;
  const float mu = (float)m;
  const float rs = rsqrtf((float)(lnst[1]/(double)kNH - m*m) + kEps);
  float acc = 0.f;
  if (t < kH){
    float z = (tnh[(long)n*kH + t] - mu)*(rs*ln[t]) + ln[kH + t];
    float wv = linW[t];
    float zw = wv*z;
    long off = (long)n*kH + t;
    u16 h1 = f2bf(zw);
    zwh[off] = h1; zwl[off] = f2bf(zw - bf2f(h1));
    u16 h2 = f2bf(z);
    zzh[off] = h2; zzl[off] = f2bf(z - bf2f(h2));
    acc = zw*z;
  }
  ared[t] = acc;
  __syncthreads();
  for (int h=128; h>0; h>>=1){
    if (t < h) ared[t] += ared[t+h];
    __syncthreads();
  }
  if (t == 0) avec[n] = ared[0];
}

// tri[i][j] = (i<=j) ? sigmoid(a_i + a_j - 2*G_ij + linb) : 0 ; G = (zw)(z)^T
__global__ __launch_bounds__(256)
void bgemm_pair_kernel(const u16* __restrict__ Ah, const u16* __restrict__ Al,
                       const u16* __restrict__ Bh, const u16* __restrict__ Bl,
                       const float* __restrict__ avec, const float* __restrict__ linb,
                       float* __restrict__ tri, double* __restrict__ frob2)
{
  constexpr int TM=64, TN=64, BK=32, KK=kH;
  __shared__ u16 Ash[TM][40], Asl[TM][40], Bsh[TN][40], Bsl[TN][40];
  __shared__ float red[256];
  const int tid = threadIdx.x;
  const int m0 = blockIdx.x*TM, n0 = blockIdx.y*TN;
  if (m0 > n0 + TN - 1){  // fully-lower block: exact zeros
    for (int idx = tid; idx < TM*TN; idx += 256){
      int r = idx >> 6, c = idx & 63;
      int gm = m0 + r, gn = n0 + c;
      if (gm < kN && gn < kN) tri[(long)gm*kN + gn] = 0.f;
    }
    return;
  }
  const int w = tid>>6, lane = tid&63;
  const int wm = (w&1)*32, wn = (w>>1)*32;
  const int quad = lane>>4, lm = lane&15;
  f32x4 acc00={}, acc01={}, acc10={}, acc11={};
  const int ar = tid>>2, ac = (tid&3)*8;
  for (int k0 = 0; k0 < KK; k0 += BK){
    uint4 avh={0,0,0,0}, avl={0,0,0,0}, bvh={0,0,0,0}, bvl={0,0,0,0};
    int gk = k0 + ac;
    if (m0+ar < kN && gk < KK){
      avh = *(const uint4*)(Ah + (long)(m0+ar)*KK + gk);
      avl = *(const uint4*)(Al + (long)(m0+ar)*KK + gk);
    }
    if (n0+ar < kN && gk < KK){
      bvh = *(const uint4*)(Bh + (long)(n0+ar)*KK + gk);
      bvl = *(const uint4*)(Bl + (long)(n0+ar)*KK + gk);
    }
    __syncthreads();
    *(uint4*)&Ash[ar][ac] = avh; *(uint4*)&Asl[ar][ac] = avl;
    *(uint4*)&Bsh[ar][ac] = bvh; *(uint4*)&Bsl[ar][ac] = bvl;
    __syncthreads();
    short8 a0h = *(const short8*)&Ash[wm+lm][quad*8];
    short8 a1h = *(const short8*)&Ash[wm+16+lm][quad*8];
    short8 a0l = *(const short8*)&Asl[wm+lm][quad*8];
    short8 a1l = *(const short8*)&Asl[wm+16+lm][quad*8];
    short8 b0h = *(const short8*)&Bsh[wn+lm][quad*8];
    short8 b1h = *(const short8*)&Bsh[wn+16+lm][quad*8];
    short8 b0l = *(const short8*)&Bsl[wn+lm][quad*8];
    short8 b1l = *(const short8*)&Bsl[wn+16+lm][quad*8];
    acc00 = __builtin_amdgcn_mfma_f32_16x16x32_bf16(a0h,b0h,acc00,0,0,0);
    acc00 = __builtin_amdgcn_mfma_f32_16x16x32_bf16(a0h,b0l,acc00,0,0,0);
    acc00 = __builtin_amdgcn_mfma_f32_16x16x32_bf16(a0l,b0h,acc00,0,0,0);
    acc01 = __builtin_amdgcn_mfma_f32_16x16x32_bf16(a0h,b1h,acc01,0,0,0);
    acc01 = __builtin_amdgcn_mfma_f32_16x16x32_bf16(a0h,b1l,acc01,0,0,0);
    acc01 = __builtin_amdgcn_mfma_f32_16x16x32_bf16(a0l,b1h,acc01,0,0,0);
    acc10 = __builtin_amdgcn_mfma_f32_16x16x32_bf16(a1h,b0h,acc10,0,0,0);
    acc10 = __builtin_amdgcn_mfma_f32_16x16x32_bf16(a1h,b0l,acc10,0,0,0);
    acc10 = __builtin_amdgcn_mfma_f32_16x16x32_bf16(a1l,b0h,acc10,0,0,0);
    acc11 = __builtin_amdgcn_mfma_f32_16x16x32_bf16(a1h,b1h,acc11,0,0,0);
    acc11 = __builtin_amdgcn_mfma_f32_16x16x32_bf16(a1h,b1l,acc11,0,0,0);
    acc11 = __builtin_amdgcn_mfma_f32_16x16x32_bf16(a1l,b1h,acc11,0,0,0);
  }
  const float lb = linb[0];
  float r2 = 0.f;
  f32x4 accs[2][2] = {{acc00, acc01},{acc10, acc11}};
  #pragma unroll
  for (int ti=0; ti<2; ++ti){
    #pragma unroll
    for (int tj=0; tj<2; ++tj){
      #pragma unroll
      for (int r=0; r<4; ++r){
        int gm = m0 + wm + ti*16 + quad*4 + r;
        int gn = n0 + wn + tj*16 + lm;
        if (gm >= kN || gn >= kN) continue;
        float t = 0.f;
        if (gm <= gn){
          float marg = avec[gm] + avec[gn] - 2.f*accs[ti][tj][r] + lb;
          t = 1.f/(1.f + expf(-marg));
        }
        tri[(long)gm*kN + gn] = t;
        r2 += t*t;
      }
    }
  }
  red[tid] = r2;
  __syncthreads();
  for (int h=128; h>0; h>>=1){
    if (tid < h) red[tid] += red[tid+h];
    __syncthreads();
  }
  if (tid == 0) unsafeAtomicAdd(frob2, (double)red[0]);
}

// ---- fused pade init: papp hi/lo (straight + transposed), psq, qsq
__global__ __launch_bounds__(256)
void pade_both_kernel(const float* __restrict__ tri, const double* __restrict__ frob2,
                      u16* __restrict__ ph, u16* __restrict__ pl,
                      u16* __restrict__ th, u16* __restrict__ tl,
                      float* __restrict__ psq, float* __restrict__ qsq,
                      float P0, float P1, float Q0, float Q1)
{
  __shared__ float t[32][33];
  const float rn = (float)(1.0 / sqrt(frob2[0]));
  int r0 = blockIdx.y*32, c0 = blockIdx.x*32;
  int tr = threadIdx.x>>5, tc = threadIdx.x&31;
  for (int i=tr; i<32; i+=8){
    int r = r0+i, c = c0+tc;
    float eye = (r==c) ? 1.f : 0.f;
    float pa = eye - tri[(long)r*kN + c]*rn;
    t[i][tc] = pa;
    long off = (long)r*kN + c;
    psq[off] = P0*eye + P1*pa;
    qsq[off] = Q0*eye + Q1*pa;
    u16 h = f2bf(pa);
    ph[off] = h;
    pl[off] = f2bf(pa - bf2f(h));
  }
  __syncthreads();
  for (int i=tr; i<32; i+=8){
    int c = c0+i, r = r0+tc;
    float v = t[tc][i];
    u16 h = f2bf(v);
    th[(long)c*kN + r] = h;
    tl[(long)c*kN + r] = f2bf(v - bf2f(h));
  }
}

// ---- stream S = Sacc * sqrt(normA) into d_out
__global__ __launch_bounds__(256)
void copy_scale_kernel(const float* __restrict__ src, const double* __restrict__ frob2,
                       float* __restrict__ dst)
{
  const float fac = (float)sqrt(sqrt(frob2[0]));
  long i = (long)blockIdx.x*256 + threadIdx.x;
  if (i < kNN) __builtin_nontemporal_store(src[i]*fac, &dst[i]);
}

// ---------------------------------------------------------------- setup: fused weights/bias/zero-init
__device__ __forceinline__ float bias_comb(const float* __restrict__ b, int i){
  float v = 0.f;
  #pragma unroll
  for (int e=0;e<4;++e)
    v += (1.f-kAl)*b[(0*4+e)*kH + i] + kAl*b[(1*4+e)*kH + i] + b[(2*4+e)*kH + i];
  return v;
}

__global__ __launch_bounds__(256)
void prep_kernel(const float* __restrict__ g1w1, const float* __restrict__ g1b1,
                 const float* __restrict__ g1w2, const float* __restrict__ g1b2,
                 const float* __restrict__ g2w1, const float* __restrict__ g2b1,
                 const float* __restrict__ g2w2, const float* __restrict__ g2b2,
                 float* __restrict__ wc1, float* __restrict__ wc2,
                 float* __restrict__ wc3, float* __restrict__ wc4,
                 float* __restrict__ bs, int* __restrict__ cnt, int* __restrict__ g,
                 double* __restrict__ slots,
                 float* __restrict__ h1, float* __restrict__ h2)
{
  constexpr int EH = kE*kH, HH = kH*kH;
  long i = (long)blockIdx.x*256 + threadIdx.x;
  if (i < 12){ slots[i] = 0.0; return; } i -= 12;   // 6 LN-stat slots (2 doubles each)
  if (i < 8L*EH){ wc1[i] = g1w1[i]; return; } i -= 8L*EH;
  if (i < EH){
    float v=0.f;
    #pragma unroll
    for (int e=0;e<4;++e) v += g1w1[(long)(8+e)*EH + i];
    wc1[8L*EH+i] = v; return;
  } i -= EH;
  if (i < 8L*HH){ wc2[i] = g1w2[i]; return; } i -= 8L*HH;
  if (i < HH){
    float v=0.f;
    #pragma unroll
    for (int e=0;e<4;++e) v += g1w2[(long)(8+e)*HH + i];
    wc2[8L*HH+i] = v; return;
  } i -= HH;
  if (i < 8L*EH){ wc3[i] = g2w1[i]; return; } i -= 8L*EH;
  if (i < EH){
    float v=0.f;
    #pragma unroll
    for (int e=0;e<4;++e) v += g2w1[(long)(8+e)*EH + i];
    wc3[8L*EH+i] = v; return;
  } i -= EH;
  if (i < 8L*HH){ wc4[i] = g2w2[i]; return; } i -= 8L*HH;
  if (i < HH){
    float v=0.f;
    #pragma unroll
    for (int e=0;e<4;++e) v += g2w2[(long)(8+e)*HH + i];
    wc4[8L*HH+i] = v; return;
  } i -= HH;
  if (i < kH){ bs[i]        = bias_comb(g1b1, (int)i); return; } i -= kH;
  if (i < kH){ bs[kH+i]     = bias_comb(g1b2, (int)i); return; } i -= kH;
  if (i < kH){ bs[2*kH+i]   = bias_comb(g2b1, (int)i); return; } i -= kH;
  if (i < kH){ bs[3*kH+i]   = bias_comb(g2b2, (int)i); return; } i -= kH;
  if (i < 8L*kN){ cnt[i] = 0; return; } i -= 8L*kN;
  if (i < 4L*kN){ g[i] = -1; return; } i -= 4L*kN;
  // zero s_times_h accumulators (EPI_ACC dests, written exactly once per launch)
  if (i < (long)kN*kE){ h1[i] = 0.f; return; } i -= (long)kN*kE;
  if (i < (long)kN*kE){ h2[i] = 0.f; return; }
}

// ---------------------------------------------------------------- CSR build (8 lists) + gmax fused
__global__ void edge_cg_kernel(const int* __restrict__ e0, const int* __restrict__ e1,
                               const int* __restrict__ e2, const int* __restrict__ e3,
                               int* __restrict__ cnt, int* __restrict__ g){
  const int* eis[4] = {e0,e1,e2,e3};
  const int e = blockIdx.y;
  const int* ei = eis[e];
  int j = blockIdx.x*256 + threadIdx.x;
  if (j >= kNE) return;
  int s = ei[j], d = ei[kNE + j];
  atomicAdd(&cnt[e*kN + d], 1);
  atomicAdd(&cnt[(4+e)*kN + s], 1);
  atomicMax(&g[e*kN + d], s);
}

// fused: blocks 0-7 = csr exclusive scans (LDS-staged); blocks 8-11 = gmax scan + h binsearch
__global__ __launch_bounds__(256)
void scan12_kernel(const int* __restrict__ cnt, int* __restrict__ offs, int* __restrict__ cur,
                   int* __restrict__ g, int* __restrict__ h){
  __shared__ int buf[kN+1];
  const int b = blockIdx.x, t = threadIdx.x;
  if (b < 8){
    for (int i=t; i<kN; i+=256) buf[i] = cnt[b*kN + i];
    __syncthreads();
    if (t == 0){
      int acc = 0;
      for (int i=0;i<kN;++i){ int c = buf[i]; buf[i] = acc; acc += c; }
      buf[kN] = acc;
    }
    __syncthreads();
    for (int i=t; i<kN; i+=256){ offs[b*(kN+1)+i] = buf[i]; cur[b*kN+i] = buf[i]; }
    if (t == 0) offs[b*(kN+1)+kN] = buf[kN];
  } else {
    const int e = b - 8;
    for (int i=t; i<kN; i+=256) buf[i] = g[e*kN + i];
    __syncthreads();
    if (t == 0){
      int m = -1;
      for (int i=0;i<kN;++i){ m = max(m, buf[i]); buf[i] = m; }
    }
    __syncthreads();
    for (int i=t; i<kN; i+=256) g[e*kN + i] = buf[i];
    for (int d=t; d<kN; d+=256){
      int lo = 0, hi = kN;
      while (lo < hi){ int mid = (lo+hi)>>1; if (buf[mid] >= d) hi = mid; else lo = mid+1; }
      h[e*kN + d] = lo;
    }
  }
}

__global__ void edge_fill_kernel(const int* __restrict__ e0, const int* __restrict__ e1,
                                 const int* __restrict__ e2, const int* __restrict__ e3,
                                 int* __restrict__ cur, int* __restrict__ adj){
  const int* eis[4] = {e0,e1,e2,e3};
  const int e = blockIdx.y;
  const int* ei = eis[e];
  int j = blockIdx.x*256 + threadIdx.x;
  if (j >= kNE) return;
  int s = ei[j], d = ei[kNE + j];
  int p = atomicAdd(&cur[e*kN + d], 1);
  adj[(long)e*kNE + p] = s;
  int q = atomicAdd(&cur[(4+e)*kN + s], 1);
  adj[(long)(4+e)*kNE + q] = d;
}

// CSR gather (sparse): t = Y[8] + bsum + 0.5*msgs; LN stats -> slot (fp64 atomics)
// Adjacency indices are staged into LDS (parallel, one latency) so the per-thread
// Y-row loads have no dependent address chain; 4-way unroll gives MLP=4.
__global__ __launch_bounds__(256)
void gather_sparse_kernel(const float* __restrict__ Y, const int* __restrict__ offs,
                          const int* __restrict__ adj, const float* __restrict__ bsum,
                          float* __restrict__ tnh, double* __restrict__ slot){
  __shared__ double ss[256], qq[256];
  __shared__ int sIdx[256];
  const int n = blockIdx.x;
  const int f = threadIdx.x;
  float acc = 0.f;
  #pragma unroll
  for (int l = 0; l < 8; ++l){
    const float* Yp = Y + (long)l*kNH;
    int b  = offs[l*(kN+1) + n];
    int cnt = offs[l*(kN+1) + n + 1] - b;
    for (int base = 0; base < cnt; base += 256){
      int lim = min(256, cnt - base);
      __syncthreads();
      if (threadIdx.x < lim) sIdx[threadIdx.x] = adj[(long)l*kNE + b + base + threadIdx.x];
      __syncthreads();
      if (f < kH){
        float a0=0.f, a1=0.f, a2=0.f, a3=0.f;
        int i = 0;
        for (; i + 4 <= lim; i += 4){
          a0 += Yp[(long)sIdx[i+0]*kH + f];
          a1 += Yp[(long)sIdx[i+1]*kH + f];
          a2 += Yp[(long)sIdx[i+2]*kH + f];
          a3 += Yp[(long)sIdx[i+3]*kH + f];
        }
        for (; i < lim; ++i) a0 += Yp[(long)sIdx[i]*kH + f];
        acc += (a0 + a1) + (a2 + a3);
      }
    }
  }
  double sp = 0.0, qp = 0.0;
  if (f < kH){
    float t = Y[(long)8*kNH + (long)n*kH + f] + bsum[f] + 0.5f*acc;
    tnh[(long)n*kH + f] = t;
    sp = t; qp = (double)t*t;
  }
  ss[threadIdx.x]=sp; qq[threadIdx.x]=qp;
  __syncthreads();
  for (int hh=128; hh>0; hh>>=1){
    if ((int)threadIdx.x < hh){ ss[threadIdx.x]+=ss[threadIdx.x+hh]; qq[threadIdx.x]+=qq[threadIdx.x+hh]; }
    __syncthreads();
  }
  if (threadIdx.x==0){
    unsafeAtomicAdd(&slot[0], ss[0]);
    unsafeAtomicAdd(&slot[1], qq[0]);
  }
}

// chunked scans over Y planes: z<4 local prefix per chunk; z>=4 local suffix per chunk.
__global__ __launch_bounds__(256)
void scan_chunk_kernel(float* __restrict__ Y, float* __restrict__ Tot){
  const int plane = blockIdx.y;     // 0..7
  const int chunk = blockIdx.x;     // 0..kNCHK-1
  const int f = threadIdx.x;
  if (f >= kH) return;
  float* P = Y + (long)plane*kNH + (long)chunk*kCH*kH + f;
  float acc = 0.f;
  if (plane < 4){
    for (int i0 = 0; i0 < kCH; i0 += 5){
      float v0 = P[(long)(i0+0)*kH], v1 = P[(long)(i0+1)*kH], v2 = P[(long)(i0+2)*kH],
            v3 = P[(long)(i0+3)*kH], v4 = P[(long)(i0+4)*kH];
      acc += v0; P[(long)(i0+0)*kH] = acc;
      acc += v1; P[(long)(i0+1)*kH] = acc;
      acc += v2; P[(long)(i0+2)*kH] = acc;
      acc += v3; P[(long)(i0+3)*kH] = acc;
      acc += v4; P[(long)(i0+4)*kH] = acc;
    }
  } else {
    for (int i0 = kCH-1; i0 >= 4; i0 -= 5){
      float v0 = P[(long)(i0-0)*kH], v1 = P[(long)(i0-1)*kH], v2 = P[(long)(i0-2)*kH],
            v3 = P[(long)(i0-3)*kH], v4 = P[(long)(i0-4)*kH];
      acc += v0; P[(long)(i0-0)*kH] = acc;
      acc += v1; P[(long)(i0-1)*kH] = acc;
      acc += v2; P[(long)(i0-2)*kH] = acc;
      acc += v3; P[(long)(i0-3)*kH] = acc;
      acc += v4; P[(long)(i0-4)*kH] = acc;
    }
  }
  Tot[((long)plane*kNCHK + chunk)*kH + f] = acc;
}

// cross-chunk scan of Tot (in place): planes<4 -> exclusive prefix over chunks;
// planes>=4 -> exclusive suffix. Makes gather_dense O(1) per plane.
__global__ __launch_bounds__(256)
void scan_tot_kernel(float* __restrict__ Tot){
  const int plane = blockIdx.x;
  const int f = threadIdx.x;
  if (f >= kH) return;
  float* T = Tot + (long)plane*kNCHK*kH + f;
  float run = 0.f;
  if (plane < 4){
    for (int c = 0; c < kNCHK; ++c){
      float v = T[(long)c*kH];
      T[(long)c*kH] = run;
      run += v;
    }
  } else {
    for (int c = kNCHK-1; c >= 0; --c){
      float v = T[(long)c*kH];
      T[(long)c*kH] = run;
      run += v;
    }
  }
}

// dense gather: t = Y[8] + bsum + 0.5*(staircase sums); Tot holds exclusive
// prefix/suffix per chunk -> 2 loads per plane. LN stats -> slot (fp64 atomics)
__global__ __launch_bounds__(256)
void gather_dense_kernel(const float* __restrict__ Y, const int* __restrict__ g,
                         const int* __restrict__ h, const float* __restrict__ bsum,
                         const float* __restrict__ Tot,
                         float* __restrict__ tnh, double* __restrict__ slot){
  __shared__ double ss[256], qq[256];
  long idx = (long)blockIdx.x*256 + threadIdx.x;
  double s = 0.0, q = 0.0;
  if (idx < kNH){
    int n = (int)(idx / kH), f = (int)(idx % kH);
    float v = 0.f;
    #pragma unroll
    for (int e = 0; e < 4; ++e){
      int gi = g[e*kN + n];
      if (gi >= 0){
        int cg = (int)((unsigned)gi / (unsigned)kCH);
        v += Y[(long)e*kNH + (long)gi*kH + f] + Tot[((long)e*kNCHK + cg)*kH + f];
      }
      int hi = h[e*kN + n];
      if (hi < kN){
        int ch = (int)((unsigned)hi / (unsigned)kCH);
        v += Y[(long)(4+e)*kNH + (long)hi*kH + f] + Tot[((long)(4+e)*kNCHK + ch)*kH + f];
      }
    }
    float t = Y[(long)8*kNH + idx] + bsum[f] + 0.5f*v;
    tnh[idx] = t;
    s = t; q = (double)t*t;
  }
  ss[threadIdx.x]=s; qq[threadIdx.x]=q;
  __syncthreads();
  for (int hh=128; hh>0; hh>>=1){
    if ((int)threadIdx.x < hh){ ss[threadIdx.x]+=ss[threadIdx.x+hh]; qq[threadIdx.x]+=qq[threadIdx.x+hh]; }
    __syncthreads();
  }
  if (threadIdx.x==0){
    unsafeAtomicAdd(&slot[0], ss[0]);
    unsafeAtomicAdd(&slot[1], qq[0]);
  }
}

// ---- invert the 16 diagonal 50x50 upper-tri blocks of U into W
__global__ __launch_bounds__(64)
void invdiag_kernel(const float* __restrict__ U, float* __restrict__ W){
  __shared__ float Us[kDB][kDB+1];
  __shared__ float Xs[kDB][kDB+1];
  const int base = blockIdx.x * kDB;
  const int tid = threadIdx.x;
  for (int idx = tid; idx < kDB*kDB; idx += 64){
    int r = idx / kDB, c = idx % kDB;
    Us[r][c] = U[(long)(base+r)*kN + base + c];
  }
  __syncthreads();
  const int c = tid;
  for (int i = kDB-1; i >= 0; --i){
    if (c < kDB){
      float x;
      if (c < i) x = 0.f;
      else {
        float s = 0.f;
        for (int k = i+1; k < kDB; ++k) s = fmaf(Us[i][k], Xs[k][c], s);
        x = (((c==i)?1.f:0.f) - s) / Us[i][i];
      }
      Xs[i][c] = x;
    }
    __syncthreads();
  }
  for (int idx = tid; idx < kDB*kDB; idx += 64){
    int r = idx / kDB, cc = idx % kDB;
    W[(long)(base+r)*kN + base + cc] = Xs[r][cc];
  }
}

// ---- fused merge for level S: one block per pair
template<int S>
__global__ __launch_bounds__(256)
void merge_fused_kernel(const float* __restrict__ U, float* __restrict__ W){
  __shared__ float Us[S][S+1];
  __shared__ float Wb[S][S+1];
  __shared__ float T[S][S+1];
  const long base = (long)blockIdx.x * (2*S) * (kN+1);
  const int tid = threadIdx.x;
  for (int idx = tid; idx < S*S; idx += 256){
    int r = idx / S, c = idx % S;
    Us[r][c] = U[base + (long)r*kN + S + c];
    Wb[r][c] = W[base + (long)(S+r)*kN + S + c];
  }
  __syncthreads();
  for (int idx = tid; idx < S*S; idx += 256){
    int r = idx / S, c = idx % S;
    float s = 0.f;
    for (int k = 0; k <= c; ++k) s = fmaf(Us[r][k], Wb[k][c], s);
    T[r][c] = s;
  }
  __syncthreads();
  for (int idx = tid; idx < S*S; idx += 256){
    int r = idx / S, c = idx % S;
    Us[r][c] = W[base + (long)r*kN + c];
  }
  __syncthreads();
  for (int idx = tid; idx < S*S; idx += 256){
    int r = idx / S, c = idx % S;
    float s = 0.f;
    for (int k = r; k < S; ++k) s = fmaf(Us[r][k], T[k][c], s);
    W[base + (long)r*kN + S + c] = -s;
  }
}

// ---- parallel column partial sums of tnh (feeds pool_head; LN commutes with mean)
__global__ __launch_bounds__(256)
void colsum_kernel(const float* __restrict__ tnh, float* __restrict__ colpart){
  const int b = blockIdx.x;          // 0..49, 16 rows each
  const int f = threadIdx.x;
  if (f >= kH) return;
  const float* P = tnh + (long)b*16*kH + f;
  float acc = 0.f;
  #pragma unroll
  for (int i = 0; i < 16; ++i) acc += P[(long)i*kH];
  colpart[(long)b*kH + f] = acc;
}

// pool + classifier + log_softmax, from column partial sums (LN applied to the mean)
__global__ __launch_bounds__(256)
void pool_head_kernel(const float* __restrict__ colpart, const double* __restrict__ lnst,
                      const float* __restrict__ ln,
                      const float* __restrict__ W, const float* __restrict__ b,
                      float* __restrict__ out){
  __shared__ float x2[kH];
  __shared__ float lg[kNC];
  int t = threadIdx.x;
  double m = lnst[0]/(double)kNH;
  const float mu = (float)m;
  const float rs = rsqrtf((float)(lnst[1]/(double)kNH - m*m) + kEps);
  if (t < kH){
    float sum = 0.f;
    for (int bb = 0; bb < 50; ++bb) sum += colpart[(long)bb*kH + t];
    float v = (sum * (1.f/(float)kN) - mu)*(rs*ln[t]) + ln[kH+t];
    x2[t] = v;
    out[t] = v;
  }
  __syncthreads();
  if (t < kNC){
    float sv = b[t];
    for (int f = 0; f < kH; ++f) sv = fmaf(x2[f], W[f*kNC + t], sv);
    lg[t] = sv;
  }
  __syncthreads();
  if (t == 0){
    float m2 = -1e30f;
    for (int c=0;c<kNC;++c) m2 = fmaxf(m2, lg[c]);
    float se = 0.f;
    for (int c=0;c<kNC;++c) se += expf(lg[c]-m2);
    float lse = m2 + logf(se);
    for (int c=0;c<kNC;++c) out[kH + c] = lg[c]-lse;
  }
}

// ---------------------------------------------------------------- host: Pade [5/5] of sqrt(1-x)
static void pade_coeffs(float* P, float* Q){
  double b[11]; b[0] = 1.0;
  for (int k=1;k<11;++k) b[k] = b[k-1]*(0.5-(k-1))/k;
  double c[11];
  for (int k=0;k<11;++k) c[k] = b[k]*((k&1)?-1.0:1.0);
  double A[5][5], rhs[5];
  for (int i=0;i<5;++i){ for (int j=0;j<5;++j) A[i][j] = c[5+i-j]; rhs[i] = -c[6+i]; }
  for (int col=0; col<5; ++col){
    int p = col;
    for (int r=col+1;r<5;++r) if (fabs(A[r][col]) > fabs(A[p][col])) p = r;
    if (p != col){
      for (int j=0;j<5;++j){ double t=A[col][j]; A[col][j]=A[p][j]; A[p][j]=t; }
      double t=rhs[col]; rhs[col]=rhs[p]; rhs[p]=t;
    }
    for (int r=col+1;r<5;++r){
      double f = A[r][col]/A[col][col];
      for (int j=col;j<5;++j) A[r][j] -= f*A[col][j];
      rhs[r] -= f*rhs[col];
    }
  }
  double q[6]; q[0] = 1.0;
  for (int r=4;r>=0;--r){
    double s = rhs[r];
    for (int j=r+1;j<5;++j) s -= A[r][j]*q[1+j];
    q[1+r] = s/A[r][r];
  }
  double p[6];
  for (int k=0;k<6;++k){
    double s = 0.0; int jm = k<5?k:5;
    for (int j=0;j<=jm;++j) s += q[j]*c[k-j];
    p[k] = s;
  }
  for (int k=0;k<6;++k){ P[k]=(float)p[k]; Q[k]=(float)q[k]; }
}

// ---------------------------------------------------------------- launch
extern "C" void kernel_launch(void* const* d_in, const int* in_sizes, int n_in,
                              void* d_out, int out_size, void* d_ws, size_t ws_size,
                              hipStream_t stream)
{
  const float* x_note = (const float*)d_in[0];
  const float* embW   = (const float*)d_in[1];
  const float* embB   = (const float*)d_in[2];
  const float* g1w1   = (const float*)d_in[3];
  const float* g1b1   = (const float*)d_in[4];
  const float* g1w2   = (const float*)d_in[5];
  const float* g1b2   = (const float*)d_in[6];
  const float* g1ln   = (const float*)d_in[7];
  const float* g2w1   = (const float*)d_in[8];
  const float* g2b1   = (const float*)d_in[9];
  const float* g2w2   = (const float*)d_in[10];
  const float* g2b2   = (const float*)d_in[11];
  const float* g2ln   = (const float*)d_in[12];
  const float* linW   = (const float*)d_in[13];
  const float* linb   = (const float*)d_in[14];
  const float* clfW   = (const float*)d_in[15];
  const float* clfb   = (const float*)d_in[16];
  const int*  e0     = (const int*)d_in[17];
  const int*  e1     = (const int*)d_in[18];
  const int*  e2     = (const int*)d_in[19];
  const int*  e3     = (const int*)d_in[20];
  float* out = (float*)d_out;

  // header: scald @0 (frob2 at [3], 6 LN slots at [8..19])
  constexpr long o_h0   = 4096;
  constexpr long o_h1   = o_h0   + (long)kN*kE;
  constexpr long o_h2   = o_h1   + (long)kN*kE;
  constexpr long o_tnh  = o_h2   + (long)kN*kE;
  constexpr long o_pp   = o_tnh  + kNH;             // 4 u16 planes = 2*kNH floats
  constexpr long o_av   = o_pp   + 2*kNH;           // kN floats
  constexpr long o_big  = o_av   + kN;              // 4*kNN floats
  constexpr long o_tri  = o_big  + 4*kNN;
  constexpr long o_sacc = o_tri  + kNN;
  constexpr long o_winv = o_sacc + kNN;
  constexpr long o_psq  = o_winv + kNN;
  constexpr long o_qsq  = o_psq  + kNN;
  constexpr long o_g    = o_qsq  + kNN;
  constexpr long o_hh   = o_g    + 4*kN;
  constexpr long o_wc1  = o_hh   + 4*kN;
  constexpr long o_wc2  = o_wc1  + 9L*kE*kH;
  constexpr long o_wc3  = o_wc2  + 9L*kH*kH;
  constexpr long o_wc4  = o_wc3  + 9L*kE*kH;
  constexpr long o_bs   = o_wc4  + 9L*kH*kH;
  constexpr long o_cnt  = o_bs   + 4*kH;
  constexpr long o_offs = o_cnt  + 8*kN;
  constexpr long o_cur  = o_offs + 8*(kN+1);
  constexpr long o_adj  = o_cur  + 8*kN;
  constexpr long o_end  = o_adj  + 8*(long)kNE;

  if (ws_size < (size_t)o_end*sizeof(float) || out_size < 215 + 2*(int)kNN || n_in < 21){
    fprintf(stderr, "kernel_launch guard: ws=%zu need=%zu out=%d need=%d n_in=%d\n",
            ws_size, (size_t)o_end*sizeof(float), out_size, (int)(215+2*kNN), n_in);
    hipMemsetAsync(d_out, 0, (size_t)out_size*sizeof(float), stream);
    return;
  }

  float* ws = (float*)d_ws;
  double* scald = (double*)d_ws;
  double* slots = scald + 8;   // 6 slots x 2 doubles
  float *h0=ws+o_h0, *h1=ws+o_h1, *h2=ws+o_h2, *tnh=ws+o_tnh,
        *big=ws+o_big, *tri=ws+o_tri, *Sacc=ws+o_sacc, *winv=ws+o_winv,
        *psq=ws+o_psq, *qsq=ws+o_qsq;
  u16* zwh = (u16*)(ws + o_pp);
  u16* zwl = zwh + kNH;
  u16* zzh = zwl + kNH;
  u16* zzl = zzh + kNH;
  float* avec = ws + o_av;
  int* gArr = (int*)(ws + o_g);
  int* hArr = (int*)(ws + o_hh);
  float *wc1=ws+o_wc1, *wc2=ws+o_wc2, *wc3=ws+o_wc3, *wc4=ws+o_wc4, *bs=ws+o_bs;
  int* cntA = (int*)(ws + o_cnt);
  int* offsA= (int*)(ws + o_offs);
  int* curA = (int*)(ws + o_cur);
  int* adjA = (int*)(ws + o_adj);
  u16* papp_h = (u16*)big;
  u16* papp_l = papp_h + kNN;
  u16* pT_h   = papp_l + kNN;
  u16* pT_l   = pT_h + kNN;
  u16* pwA_h  = pT_l + kNN;
  u16* pwA_l  = pwA_h + kNN;
  u16* pwB_h  = pwA_l + kNN;
  u16* pwB_l  = pwB_h + kNN;
  // transient buffers carved from big's slack (big holds 9*kNH Y-planes during layers).
  float* totbuf  = big + (long)9*kNH;                // 8*kNCHK*kH = 25600 floats
  float* colpart = totbuf + (long)8*kNCHK*kH;        // 50*kH = 10000 floats

  float P[6], Q[6];
  pade_coeffs(P, Q);

  auto eg = [](long n){ return dim3((unsigned)((n+255)/256)); };

  // one batch-9 GEMM per layer; lnst!=null -> LN fused into A-load (reads raw tnh)
  auto layer_gemm = [&](const float* hin, int K, const float* wcat,
                        const float* lnp, const double* lnst){
    if (lnst)
      launch_gemm<false,false,EPI_NONE,true>(stream, hin, K, wcat, kH, big, kH,
          kN, kH, K, 9, 0, (long)K*kH, kNH, 0.f, nullptr, 0, nullptr, lnp, lnst);
    else
      launch_gemm<false,false,EPI_NONE>(stream, hin, K, wcat, kH, big, kH,
          kN, kH, K, 9, 0, (long)K*kH, kNH, 0.f);
  };
  auto sparse_layer = [&](const float* hin, int K, const float* wcat, const float* bsum,
                          const float* lnp, const double* lnst, double* slotW){
    layer_gemm(hin, K, wcat, lnp, lnst);
    gather_sparse_kernel<<<dim3(kN),256,0,stream>>>(big, offsA, adjA, bsum, tnh, slotW);
  };
  auto dense_layer = [&](const float* hin, int K, const float* wcat, const float* bsum,
                         const float* lnp, const double* lnst, double* slotW){
    layer_gemm(hin, K, wcat, lnp, lnst);
    scan_chunk_kernel<<<dim3(kNCHK,8),256,0,stream>>>(big, totbuf);
    scan_tot_kernel<<<dim3(8),256,0,stream>>>(totbuf);
    gather_dense_kernel<<<kGB,256,0,stream>>>(big, gArr, hArr, bsum, totbuf, tnh, slotW);
  };
  // NOTE: winv and Sacc MUST be zeroed per call — the level-400 step and Sacc use
  // EPI_ACC (atomic accumulate). They are CONTIGUOUS in the workspace (Sacc then
  // winv), so one fill covers both. tri's fill must stay AFTER the s=100/200
  // levels (they use tri as scratch).
  // Lesson (R8): keep the K-split GEMM path for s=100/200 — a fused per-pair
  // kernel without register tiling ran 10x slower (serial k-chains + LDS bank
  // conflicts). Low dispatch count loses to per-dispatch efficiency here.
  auto blocked_trsm = [&](){
    hipMemsetAsync(Sacc, 0, (size_t)(2*kNN)*sizeof(float), stream);  // Sacc + winv
    invdiag_kernel<<<dim3(kN/kDB),64,0,stream>>>(qsq, winv);
    merge_fused_kernel<50><<<dim3(kN/100),256,0,stream>>>(qsq, winv);
    {   // level s=100 (4 pairs)
      int s = 100, npairs = 4;
      long step = (long)2*s*kN + 2*s;
      launch_gemm<false,true,EPI_NONE>(stream,
          qsq + s, kN, winv + (long)s*kN + s, kN, tri, s,
          s, s, s, npairs, step, step, (long)s*s, 0.f);
      launch_gemm<true,false,EPI_SCALE>(stream,
          winv, kN, tri, s, winv + s, kN,
          s, s, s, npairs, step, (long)s*s, step, -1.f);
    }
    {   // level s=200 (2 pairs)
      int s = 200, npairs = 2;
      long step = (long)2*s*kN + 2*s;
      launch_gemm<false,true,EPI_NONE>(stream,
          qsq + s, kN, winv + (long)s*kN + s, kN, tri, s,
          s, s, s, npairs, step, step, (long)s*s, 0.f);
      launch_gemm<true,false,EPI_SCALE>(stream,
          winv, kN, tri, s, winv + s, kN,
          s, s, s, npairs, step, (long)s*s, step, -1.f);
    }
    {   // level s=400 (1 pair) — K-split x4, atomic ACC
      hipMemsetAsync(tri, 0, (size_t)400*400*sizeof(float), stream);
      launch_gemm<false,true,EPI_ACC>(stream,
          qsq + 400, kN, winv + (long)400*kN + 400, kN, tri, 400,
          400, 400, 100, 4, 100, (long)100*kN, 0, 1.f, nullptr, 100);
      launch_gemm<true,false,EPI_ACC>(stream,
          winv, kN, tri, 400, winv + 400, kN,
          400, 400, 100, 4, 100, (long)100*400, 0, -1.f, nullptr, 100);
    }
    launch_gemm<true,true,EPI_ACC>(stream,
        winv, kN, psq, kN, Sacc, kN, kN, kN, 100, 8,
        100, (long)100*kN, 0, 1.f, nullptr, 100);
  };
  // consumes raw tnh (LN stats from lnst slot); prep zeroes frob2
  auto run_pair_mpa = [&](const double* lnst, const float* lnp, float* SoutDst){
    ln_pair_prep_kernel<<<dim3(kN),256,0,stream>>>(tnh, lnst, lnp, linW,
                                                   zwh, zwl, zzh, zzl, avec, scald+3);
    bgemm_pair_kernel<<<dim3(13,13),256,0,stream>>>(zwh, zwl, zzh, zzl, avec, linb,
                                                    tri, scald+3);
    pade_both_kernel<<<dim3(25,25),256,0,stream>>>(tri, scald+3, papp_h, papp_l, pT_h, pT_l,
                                                   psq, qsq, P[0],P[1],Q[0],Q[1]);
    dim3 g13(13,13,1);
    bgemm2_kernel<<<g13,256,0,stream>>>(papp_h,papp_l, pT_h,pT_l, psq,qsq, pwA_h,pwA_l, P[2],Q[2]);
    bgemm2_kernel<<<g13,256,0,stream>>>(pwA_h,pwA_l,  pT_h,pT_l, psq,qsq, pwB_h,pwB_l, P[3],Q[3]);
    bgemm2_kernel<<<g13,256,0,stream>>>(pwB_h,pwB_l,  pT_h,pT_l, psq,qsq, pwA_h,pwA_l, P[4],Q[4]);
    bgemm2_kernel<<<g13,256,0,stream>>>(pwA_h,pwA_l,  pT_h,pT_l, psq,qsq, nullptr,nullptr, P[5],Q[5]);
    blocked_trsm();
    copy_scale_kernel<<<eg(kNN),256,0,stream>>>(Sacc, scald+3, SoutDst);
  };
  // h1/h2 are zeroed once in prep_kernel (each is accumulated exactly once per launch)
  auto s_times_h = [&](const float* hin, float* hout){
    launch_gemm<true,false,EPI_ACC>(stream,
        Sacc, kN, hin, kE, hout, kE, kN, kE, 100, 8,
        100, (long)100*kE, 0, 1.f, nullptr, 100, scald+3);
  };

  float* S1f = out + 215;
  float* S2f = out + 215 + kNN;

  // ---- setup: fused prep (incl. slot + h1/h2 zeroing), CSR build
  {
    constexpr long prep_span = 12 + 2L*(9L*kE*kH + 9L*kH*kH) + 4L*kH + 8L*kN + 4L*kN
                               + 2L*kN*kE;
    prep_kernel<<<eg(prep_span),256,0,stream>>>(g1w1, g1b1, g1w2, g1b2,
                                                g2w1, g2b1, g2w2, g2b2,
                                                wc1, wc2, wc3, wc4, bs, cntA, gArr, slots,
                                                h1, h2);
  }
  edge_cg_kernel<<<dim3((kNE+255)/256,4),256,0,stream>>>(e0,e1,e2,e3, cntA, gArr);
  scan12_kernel<<<dim3(12),256,0,stream>>>(cntA, offsA, curA, gArr, hArr);
  edge_fill_kernel<<<dim3((kNE+255)/256,4),256,0,stream>>>(e0,e1,e2,e3, curA, adjA);

  // ---- embed (lda=111 -> scalar-load fallback path inside kernel)
  launch_gemm<false,false,EPI_BIAS>(stream, x_note, kF, embW, kE, h0, kE, kN, kE, kF, 1,
                                    0,0,0, 0.f, embB);

  // ---- GNN1 (sparse); layer 2 reads raw tnh with LN fused into GEMM
  sparse_layer(h0,  kE, wc1, bs,      nullptr, nullptr,  slots+0);
  sparse_layer(tnh, kH, wc2, bs+kH,   g1ln,    slots+0,  slots+2);

  // ---- S1 (LN(g1ln[1]) fused into pair prep)
  run_pair_mpa(slots+2, g1ln + 2*kH, S1f);

  // ---- h1 = S1 @ h0
  s_times_h(h0, h1);

  // ---- GNN2 #1 (dense)
  dense_layer(h1,  kE, wc3, bs+2*kH, nullptr, nullptr,  slots+4);
  dense_layer(tnh, kH, wc4, bs+3*kH, g2ln,    slots+4,  slots+6);

  // ---- S2
  run_pair_mpa(slots+6, g2ln + 2*kH, S2f);

  // ---- h2 = S2 @ h1
  s_times_h(h1, h2);

  // ---- GNN2 #2 (dense; mask2 == mask1)
  dense_layer(h2,  kE, wc3, bs+2*kH, nullptr, nullptr,  slots+8);
  dense_layer(tnh, kH, wc4, bs+3*kH, g2ln,    slots+8,  slots+10);

  // ---- pool + classifier + log_softmax (LN fused; pooling via parallel colsums)
  colsum_kernel<<<dim3(50),256,0,stream>>>(tnh, colpart);
  pool_head_kernel<<<dim3(1),256,0,stream>>>(colpart, slots+10, g2ln + 2*kH, clfW, clfb, out);
}

// Round 11
// 931.998 us; speedup vs baseline: 1.0146x; 1.0146x over previous
//
#include <hip/hip_runtime.h>
#include <hip/hip_bf16.h>
#include <math.h>
#include <stdio.h>

static constexpr int   kN  = 800;    // nodes
static constexpr int   kF  = 111;    // input features
static constexpr int   kE  = 32;     // embed dim
static constexpr int   kH  = 200;    // hidden
static constexpr int   kNC = 15;     // classes
static constexpr int   kNE = 8000;   // edges per type
static constexpr long  kNN = (long)kN*kN;   // 640000
static constexpr long  kNH = (long)kN*kH;   // 160000
static constexpr float kAl  = 0.5f;  // ALPHA
static constexpr float kEps = 1e-5f;
static constexpr int   kGB  = (int)((kNH+255)/256);  // gather blocks = 625
static constexpr int   kDB  = 50;    // trsm diagonal block size
static constexpr int   kCH  = 50;    // scan chunk size (nodes)
static constexpr int   kNCHK= kN/kCH; // 16 chunks

typedef unsigned short u16;
typedef __attribute__((ext_vector_type(8))) short short8;
typedef __attribute__((ext_vector_type(4))) float f32x4;

__device__ __forceinline__ u16 f2bf(float v){
  __hip_bfloat16 b = __float2bfloat16(v);
  return *reinterpret_cast<u16*>(&b);
}
__device__ __forceinline__ float bf2f(u16 h){
  unsigned int u = ((unsigned int)h) << 16;
  float f; __builtin_memcpy(&f, &u, 4);
  return f;
}

enum { EPI_NONE=0, EPI_BIAS=1, EPI_SCALE=4, EPI_ACC=6 };

// ---------------------------------------------------------------- fp32 GEMM (software-pipelined, float4 loads)
// LNA: apply graph-LN to A on load: a' = (a - mu)*(rs*lnw[k]) + lnw[kH+k];
// stats read directly from lnst (2 doubles: sum, sumsq — atomically accumulated upstream).
template<bool TRIUA, bool TRIUB, int EPI, bool LNA>
__global__ __launch_bounds__(256)
void gemm_kernel(const float* __restrict__ A, int lda,
                 const float* __restrict__ B, int ldb,
                 float* __restrict__ C, int ldc,
                 int M, int Ncl, int K,
                 long sA, long sB, long sC, float scale,
                 const float* __restrict__ bias, int kstep,
                 const double* __restrict__ scalp,
                 const float* __restrict__ lnw,
                 const double* __restrict__ lnst)
{
  constexpr int TM=64, TN=64, TK=16;
  A += (long)blockIdx.z * sA;
  B += (long)blockIdx.z * sB;
  C += (long)blockIdx.z * sC;
  __shared__ __align__(16) float As[TK][TM+4];
  __shared__ __align__(16) float Bs[TK][TN+4];
  const int tid = threadIdx.x;
  const int tn4 = (tid & 15)*4, tm4 = (tid >> 4)*4;
  const int m0 = blockIdx.x * TM, n0 = blockIdx.y * TN;
  float acc[4][4] = {};
  float mu = 0.f, rsf = 1.f;
  if (LNA){
    double m = lnst[0]/(double)kNH;
    double var = lnst[1]/(double)kNH - m*m;
    mu = (float)m;
    rsf = rsqrtf((float)var + kEps);
  }
  const int kbase = kstep ? (int)blockIdx.z * kstep : 0;
  int k0 = TRIUA ? max(m0 - kbase, 0) : 0;
  int kEnd = TRIUB ? min(K, n0 + TN - kbase) : K;
  const bool skip = (k0 >= kEnd);
  if (skip && EPI == EPI_ACC) return;
  if (!skip) {
    // thread->element maps: A: row am, cols ak..ak+3 ; B: row bk, cols bn..bn+3
    const int am = tid >> 2, ak = (tid & 3) * 4;
    const int bk = tid >> 4, bn = (tid & 15) * 4;
    const bool avec = ((lda & 3) == 0);
    const bool bvec = ((ldb & 3) == 0);
    float4 av, bv;
    auto loadT = [&](int kk0){
      av = make_float4(0.f,0.f,0.f,0.f);
      bv = make_float4(0.f,0.f,0.f,0.f);
      {
        int gm = m0 + am, gk = kk0 + ak;
        if (gm < M && gk < K){
          if (avec && (gk + 4 <= K)){
            av = *(const float4*)(A + (long)gm*lda + gk);
            if (LNA){
              av.x = (av.x - mu)*(rsf*lnw[gk+0]) + lnw[kH+gk+0];
              av.y = (av.y - mu)*(rsf*lnw[gk+1]) + lnw[kH+gk+1];
              av.z = (av.z - mu)*(rsf*lnw[gk+2]) + lnw[kH+gk+2];
              av.w = (av.w - mu)*(rsf*lnw[gk+3]) + lnw[kH+gk+3];
            }
          } else {
            float tmp[4] = {0.f,0.f,0.f,0.f};
            #pragma unroll
            for (int j=0;j<4;++j){
              int k2 = gk + j;
              if (k2 < K){
                float v = A[(long)gm*lda + k2];
                if (LNA) v = (v - mu)*(rsf*lnw[k2]) + lnw[kH + k2];
                tmp[j] = v;
              }
            }
            av = make_float4(tmp[0],tmp[1],tmp[2],tmp[3]);
          }
        }
      }
      {
        int gk = kk0 + bk, gn = n0 + bn;
        if (gk < K && gn < Ncl){
          if (bvec && (gn + 4 <= Ncl)){
            bv = *(const float4*)(B + (long)gk*ldb + gn);
          } else {
            float tmp[4] = {0.f,0.f,0.f,0.f};
            #pragma unroll
            for (int j=0;j<4;++j) if (gn+j < Ncl) tmp[j] = B[(long)gk*ldb + gn + j];
            bv = make_float4(tmp[0],tmp[1],tmp[2],tmp[3]);
          }
        }
      }
    };
    auto storeT = [&](){
      As[ak+0][am] = av.x;
      As[ak+1][am] = av.y;
      As[ak+2][am] = av.z;
      As[ak+3][am] = av.w;
      *(float4*)&Bs[bk][bn] = bv;
    };
    loadT(k0);
    for (;;){
      __syncthreads();
      storeT();
      __syncthreads();
      int kn = k0 + TK;
      bool more = kn < kEnd;
      if (more) loadT(kn);
      #pragma unroll
      for (int kk=0; kk<TK; ++kk) {
        float a[4], b[4];
        #pragma unroll
        for (int u=0;u<4;++u){ a[u]=As[kk][tm4+u]; b[u]=Bs[kk][tn4+u]; }
        #pragma unroll
        for (int i=0;i<4;++i)
          #pragma unroll
          for (int j=0;j<4;++j)
            acc[i][j] = fmaf(a[i], b[j], acc[i][j]);
      }
      if (!more) break;
      k0 = kn;
    }
  }
  float sc = scale;
  if (EPI == EPI_ACC && scalp) sc *= (float)sqrt(sqrt(scalp[0]));
  #pragma unroll
  for (int i=0;i<4;++i) {
    int gm = m0 + tm4 + i;
    if (gm >= M) continue;
    #pragma unroll
    for (int j=0;j<4;++j) {
      int gn = n0 + tn4 + j;
      if (gn >= Ncl) continue;
      float v = acc[i][j];
      long off = (long)gm*ldc + gn;
      if (EPI == EPI_BIAS)       C[off] = v + bias[gn];
      else if (EPI == EPI_SCALE) C[off] = scale*v;
      else if (EPI == EPI_ACC)   unsafeAtomicAdd(&C[off], sc*v);
      else                       C[off] = v;
    }
  }
}

template<bool TRIUA, bool TRIUB, int EPI, bool LNA = false>
static inline void launch_gemm(hipStream_t st,
                               const float* A, int lda, const float* B, int ldb,
                               float* C, int ldc, int M, int Ncl, int K, int batch,
                               long sA, long sB, long sC, float scale,
                               const float* bias = nullptr, int kstep = 0,
                               const double* scalp = nullptr,
                               const float* lnw = nullptr,
                               const double* lnst = nullptr)
{
  dim3 grid((M+63)/64, (Ncl+63)/64, batch);
  gemm_kernel<TRIUA,TRIUB,EPI,LNA><<<grid, 256, 0, st>>>(
      A,lda,B,ldb,C,ldc,M,Ncl,K,sA,sB,sC,scale,bias,kstep,scalp,lnw,lnst);
}

// ---------------------------------------------------------------- split-bf16 MFMA GEMM (powers, pipelined)
__global__ __launch_bounds__(256)
void bgemm2_kernel(const u16* __restrict__ Ah, const u16* __restrict__ Al,
                   const u16* __restrict__ Bh, const u16* __restrict__ Bl,
                   float* __restrict__ C, float* __restrict__ C2,
                   u16* __restrict__ Oh, u16* __restrict__ Ol,
                   float p0, float p1)
{
  constexpr int TM=64, TN=64, BK=32;
  __shared__ u16 Ash[TM][40], Asl[TM][40], Bsh[TN][40], Bsl[TN][40];
  const int tid = threadIdx.x;
  const int m0 = blockIdx.x*TM, n0 = blockIdx.y*TN;
  const int w = tid>>6, lane = tid&63;
  const int wm = (w&1)*32, wn = (w>>1)*32;
  const int quad = lane>>4, lm = lane&15;
  f32x4 acc00={}, acc01={}, acc10={}, acc11={};
  const bool skip = (m0 > n0 + TN - 1);
  int k0 = m0;
  const int kEnd = min(kN, n0+TN);
  const int ar = tid>>2, ac = (tid&3)*8;
  if (!skip){
    uint4 avh, avl, bvh, bvl;
    auto loadT = [&](int kk0){
      avh = {0,0,0,0}; avl = {0,0,0,0}; bvh = {0,0,0,0}; bvl = {0,0,0,0};
      int gk = kk0 + ac;
      if (m0+ar < kN && gk < kN){
        avh = *(const uint4*)(Ah + (long)(m0+ar)*kN + gk);
        avl = *(const uint4*)(Al + (long)(m0+ar)*kN + gk);
      }
      if (n0+ar < kN && gk < kN){
        bvh = *(const uint4*)(Bh + (long)(n0+ar)*kN + gk);
        bvl = *(const uint4*)(Bl + (long)(n0+ar)*kN + gk);
      }
    };
    loadT(k0);
    for (;;){
      __syncthreads();
      *(uint4*)&Ash[ar][ac] = avh; *(uint4*)&Asl[ar][ac] = avl;
      *(uint4*)&Bsh[ar][ac] = bvh; *(uint4*)&Bsl[ar][ac] = bvl;
      __syncthreads();
      int kn = k0 + BK;
      bool more = kn < kEnd;
      if (more) loadT(kn);
      short8 a0h = *(const short8*)&Ash[wm+lm][quad*8];
      short8 a1h = *(const short8*)&Ash[wm+16+lm][quad*8];
      short8 a0l = *(const short8*)&Asl[wm+lm][quad*8];
      short8 a1l = *(const short8*)&Asl[wm+16+lm][quad*8];
      short8 b0h = *(const short8*)&Bsh[wn+lm][quad*8];
      short8 b1h = *(const short8*)&Bsh[wn+16+lm][quad*8];
      short8 b0l = *(const short8*)&Bsl[wn+lm][quad*8];
      short8 b1l = *(const short8*)&Bsl[wn+16+lm][quad*8];
      acc00 = __builtin_amdgcn_mfma_f32_16x16x32_bf16(a0h,b0h,acc00,0,0,0);
      acc00 = __builtin_amdgcn_mfma_f32_16x16x32_bf16(a0h,b0l,acc00,0,0,0);
      acc00 = __builtin_amdgcn_mfma_f32_16x16x32_bf16(a0l,b0h,acc00,0,0,0);
      acc01 = __builtin_amdgcn_mfma_f32_16x16x32_bf16(a0h,b1h,acc01,0,0,0);
      acc01 = __builtin_amdgcn_mfma_f32_16x16x32_bf16(a0h,b1l,acc01,0,0,0);
      acc01 = __builtin_amdgcn_mfma_f32_16x16x32_bf16(a0l,b1h,acc01,0,0,0);
      acc10 = __builtin_amdgcn_mfma_f32_16x16x32_bf16(a1h,b0h,acc10,0,0,0);
      acc10 = __builtin_amdgcn_mfma_f32_16x16x32_bf16(a1h,b0l,acc10,0,0,0);
      acc10 = __builtin_amdgcn_mfma_f32_16x16x32_bf16(a1l,b0h,acc10,0,0,0);
      acc11 = __builtin_amdgcn_mfma_f32_16x16x32_bf16(a1h,b1h,acc11,0,0,0);
      acc11 = __builtin_amdgcn_mfma_f32_16x16x32_bf16(a1h,b1l,acc11,0,0,0);
      acc11 = __builtin_amdgcn_mfma_f32_16x16x32_bf16(a1l,b1h,acc11,0,0,0);
      if (!more) break;
      k0 = kn;
    }
  }
  f32x4 accs[2][2] = {{acc00, acc01},{acc10, acc11}};
  #pragma unroll
  for (int ti=0; ti<2; ++ti){
    #pragma unroll
    for (int tj=0; tj<2; ++tj){
      #pragma unroll
      for (int r=0; r<4; ++r){
        int gm = m0 + wm + ti*16 + quad*4 + r;
        int gn = n0 + wn + tj*16 + lm;
        if (gm >= kN || gn >= kN) continue;
        float v = accs[ti][tj][r];
        long off = (long)gm*kN + gn;
        C[off]  += p0*v;
        C2[off] += p1*v;
        if (Oh){
          u16 h = f2bf(v);
          Oh[off] = h;
          Ol[off] = f2bf(v - bf2f(h));
        }
      }
    }
  }
}

// ---------------------------------------------------------------- pairwise S via MFMA
// prep: per node n, z = LN(tnh), write hi/lo of (w.*z) and z, and a[n]=sum w z^2
// also zeroes *frobz (consumed later by bgemm_pair's atomics; stream-ordered)
__global__ __launch_bounds__(256)
void ln_pair_prep_kernel(const float* __restrict__ tnh, const double* __restrict__ lnst,
                         const float* __restrict__ ln, const float* __restrict__ linW,
                         u16* __restrict__ zwh, u16* __restrict__ zwl,
                         u16* __restrict__ zzh, u16* __restrict__ zzl,
                         float* __restrict__ avec, double* __restrict__ frobz)
{
  __shared__ float ared[256];
  const int n = blockIdx.x, t = threadIdx.x;
  if (t == 0) *frobz = 0.0;   // benign same-value race across blocks
  double m = lnst[0]/(double)kNH;
  const float mu = (float)m;
  const float rs = rsqrtf((float)(lnst[1]/(double)kNH - m*m) + kEps);
  float acc = 0.f;
  if (t < kH){
    float z = (tnh[(long)n*kH + t] - mu)*(rs*ln[t]) + ln[kH + t];
    float wv = linW[t];
    float zw = wv*z;
    long off = (long)n*kH + t;
    u16 h1 = f2bf(zw);
    zwh[off] = h1; zwl[off] = f2bf(zw - bf2f(h1));
    u16 h2 = f2bf(z);
    zzh[off] = h2; zzl[off] = f2bf(z - bf2f(h2));
    acc = zw*z;
  }
  ared[t] = acc;
  __syncthreads();
  for (int h=128; h>0; h>>=1){
    if (t < h) ared[t] += ared[t+h];
    __syncthreads();
  }
  if (t == 0) avec[n] = ared[0];
}

// tri[i][j] = (i<=j) ? sigmoid(a_i + a_j - 2*G_ij + linb) : 0 ; G = (zw)(z)^T
__global__ __launch_bounds__(256)
void bgemm_pair_kernel(const u16* __restrict__ Ah, const u16* __restrict__ Al,
                       const u16* __restrict__ Bh, const u16* __restrict__ Bl,
                       const float* __restrict__ avec, const float* __restrict__ linb,
                       float* __restrict__ tri, double* __restrict__ frob2)
{
  constexpr int TM=64, TN=64, BK=32, KK=kH;
  __shared__ u16 Ash[TM][40], Asl[TM][40], Bsh[TN][40], Bsl[TN][40];
  __shared__ float red[256];
  const int tid = threadIdx.x;
  const int m0 = blockIdx.x*TM, n0 = blockIdx.y*TN;
  if (m0 > n0 + TN - 1){  // fully-lower block: exact zeros
    for (int idx = tid; idx < TM*TN; idx += 256){
      int r = idx >> 6, c = idx & 63;
      int gm = m0 + r, gn = n0 + c;
      if (gm < kN && gn < kN) tri[(long)gm*kN + gn] = 0.f;
    }
    return;
  }
  const int w = tid>>6, lane = tid&63;
  const int wm = (w&1)*32, wn = (w>>1)*32;
  const int quad = lane>>4, lm = lane&15;
  f32x4 acc00={}, acc01={}, acc10={}, acc11={};
  const int ar = tid>>2, ac = (tid&3)*8;
  for (int k0 = 0; k0 < KK; k0 += BK){
    uint4 avh={0,0,0,0}, avl={0,0,0,0}, bvh={0,0,0,0}, bvl={0,0,0,0};
    int gk = k0 + ac;
    if (m0+ar < kN && gk < KK){
      avh = *(const uint4*)(Ah + (long)(m0+ar)*KK + gk);
      avl = *(const uint4*)(Al + (long)(m0+ar)*KK + gk);
    }
    if (n0+ar < kN && gk < KK){
      bvh = *(const uint4*)(Bh + (long)(n0+ar)*KK + gk);
      bvl = *(const uint4*)(Bl + (long)(n0+ar)*KK + gk);
    }
    __syncthreads();
    *(uint4*)&Ash[ar][ac] = avh; *(uint4*)&Asl[ar][ac] = avl;
    *(uint4*)&Bsh[ar][ac] = bvh; *(uint4*)&Bsl[ar][ac] = bvl;
    __syncthreads();
    short8 a0h = *(const short8*)&Ash[wm+lm][quad*8];
    short8 a1h = *(const short8*)&Ash[wm+16+lm][quad*8];
    short8 a0l = *(const short8*)&Asl[wm+lm][quad*8];
    short8 a1l = *(const short8*)&Asl[wm+16+lm][quad*8];
    short8 b0h = *(const short8*)&Bsh[wn+lm][quad*8];
    short8 b1h = *(const short8*)&Bsh[wn+16+lm][quad*8];
    short8 b0l = *(const short8*)&Bsl[wn+lm][quad*8];
    short8 b1l = *(const short8*)&Bsl[wn+16+lm][quad*8];
    acc00 = __builtin_amdgcn_mfma_f32_16x16x32_bf16(a0h,b0h,acc00,0,0,0);
    acc00 = __builtin_amdgcn_mfma_f32_16x16x32_bf16(a0h,b0l,acc00,0,0,0);
    acc00 = __builtin_amdgcn_mfma_f32_16x16x32_bf16(a0l,b0h,acc00,0,0,0);
    acc01 = __builtin_amdgcn_mfma_f32_16x16x32_bf16(a0h,b1h,acc01,0,0,0);
    acc01 = __builtin_amdgcn_mfma_f32_16x16x32_bf16(a0h,b1l,acc01,0,0,0);
    acc01 = __builtin_amdgcn_mfma_f32_16x16x32_bf16(a0l,b1h,acc01,0,0,0);
    acc10 = __builtin_amdgcn_mfma_f32_16x16x32_bf16(a1h,b0h,acc10,0,0,0);
    acc10 = __builtin_amdgcn_mfma_f32_16x16x32_bf16(a1h,b0l,acc10,0,0,0);
    acc10 = __builtin_amdgcn_mfma_f32_16x16x32_bf16(a1l,b0h,acc10,0,0,0);
    acc11 = __builtin_amdgcn_mfma_f32_16x16x32_bf16(a1h,b1h,acc11,0,0,0);
    acc11 = __builtin_amdgcn_mfma_f32_16x16x32_bf16(a1h,b1l,acc11,0,0,0);
    acc11 = __builtin_amdgcn_mfma_f32_16x16x32_bf16(a1l,b1h,acc11,0,0,0);
  }
  const float lb = linb[0];
  float r2 = 0.f;
  f32x4 accs[2][2] = {{acc00, acc01},{acc10, acc11}};
  #pragma unroll
  for (int ti=0; ti<2; ++ti){
    #pragma unroll
    for (int tj=0; tj<2; ++tj){
      #pragma unroll
      for (int r=0; r<4; ++r){
        int gm = m0 + wm + ti*16 + quad*4 + r;
        int gn = n0 + wn + tj*16 + lm;
        if (gm >= kN || gn >= kN) continue;
        float t = 0.f;
        if (gm <= gn){
          float marg = avec[gm] + avec[gn] - 2.f*accs[ti][tj][r] + lb;
          t = 1.f/(1.f + expf(-marg));
        }
        tri[(long)gm*kN + gn] = t;
        r2 += t*t;
      }
    }
  }
  red[tid] = r2;
  __syncthreads();
  for (int h=128; h>0; h>>=1){
    if (tid < h) red[tid] += red[tid+h];
    __syncthreads();
  }
  if (tid == 0) unsafeAtomicAdd(frob2, (double)red[0]);
}

// ---- fused pade init: papp hi/lo (straight + transposed), psq, qsq
__global__ __launch_bounds__(256)
void pade_both_kernel(const float* __restrict__ tri, const double* __restrict__ frob2,
                      u16* __restrict__ ph, u16* __restrict__ pl,
                      u16* __restrict__ th, u16* __restrict__ tl,
                      float* __restrict__ psq, float* __restrict__ qsq,
                      float P0, float P1, float Q0, float Q1)
{
  __shared__ float t[32][33];
  const float rn = (float)(1.0 / sqrt(frob2[0]));
  int r0 = blockIdx.y*32, c0 = blockIdx.x*32;
  int tr = threadIdx.x>>5, tc = threadIdx.x&31;
  for (int i=tr; i<32; i+=8){
    int r = r0+i, c = c0+tc;
    float eye = (r==c) ? 1.f : 0.f;
    float pa = eye - tri[(long)r*kN + c]*rn;
    t[i][tc] = pa;
    long off = (long)r*kN + c;
    psq[off] = P0*eye + P1*pa;
    qsq[off] = Q0*eye + Q1*pa;
    u16 h = f2bf(pa);
    ph[off] = h;
    pl[off] = f2bf(pa - bf2f(h));
  }
  __syncthreads();
  for (int i=tr; i<32; i+=8){
    int c = c0+i, r = r0+tc;
    float v = t[tc][i];
    u16 h = f2bf(v);
    th[(long)c*kN + r] = h;
    tl[(long)c*kN + r] = f2bf(v - bf2f(h));
  }
}

// ---- stream S = Sacc * sqrt(normA) into d_out
__global__ __launch_bounds__(256)
void copy_scale_kernel(const float* __restrict__ src, const double* __restrict__ frob2,
                       float* __restrict__ dst)
{
  const float fac = (float)sqrt(sqrt(frob2[0]));
  long i = (long)blockIdx.x*256 + threadIdx.x;
  if (i < kNN) __builtin_nontemporal_store(src[i]*fac, &dst[i]);
}

// ---------------------------------------------------------------- setup: fused weights/bias/zero-init
__device__ __forceinline__ float bias_comb(const float* __restrict__ b, int i){
  float v = 0.f;
  #pragma unroll
  for (int e=0;e<4;++e)
    v += (1.f-kAl)*b[(0*4+e)*kH + i] + kAl*b[(1*4+e)*kH + i] + b[(2*4+e)*kH + i];
  return v;
}

__global__ __launch_bounds__(256)
void prep_kernel(const float* __restrict__ g1w1, const float* __restrict__ g1b1,
                 const float* __restrict__ g1w2, const float* __restrict__ g1b2,
                 const float* __restrict__ g2w1, const float* __restrict__ g2b1,
                 const float* __restrict__ g2w2, const float* __restrict__ g2b2,
                 float* __restrict__ wc1, float* __restrict__ wc2,
                 float* __restrict__ wc3, float* __restrict__ wc4,
                 float* __restrict__ bs, int* __restrict__ cnt, int* __restrict__ g,
                 double* __restrict__ slots)
{
  constexpr int EH = kE*kH, HH = kH*kH;
  long i = (long)blockIdx.x*256 + threadIdx.x;
  if (i < 12){ slots[i] = 0.0; return; } i -= 12;   // 6 LN-stat slots (2 doubles each)
  if (i < 8L*EH){ wc1[i] = g1w1[i]; return; } i -= 8L*EH;
  if (i < EH){
    float v=0.f;
    #pragma unroll
    for (int e=0;e<4;++e) v += g1w1[(long)(8+e)*EH + i];
    wc1[8L*EH+i] = v; return;
  } i -= EH;
  if (i < 8L*HH){ wc2[i] = g1w2[i]; return; } i -= 8L*HH;
  if (i < HH){
    float v=0.f;
    #pragma unroll
    for (int e=0;e<4;++e) v += g1w2[(long)(8+e)*HH + i];
    wc2[8L*HH+i] = v; return;
  } i -= HH;
  if (i < 8L*EH){ wc3[i] = g2w1[i]; return; } i -= 8L*EH;
  if (i < EH){
    float v=0.f;
    #pragma unroll
    for (int e=0;e<4;++e) v += g2w1[(long)(8+e)*EH + i];
    wc3[8L*EH+i] = v; return;
  } i -= EH;
  if (i < 8L*HH){ wc4[i] = g2w2[i]; return; } i -= 8L*HH;
  if (i < HH){
    float v=0.f;
    #pragma unroll
    for (int e=0;e<4;++e) v += g2w2[(long)(8+e)*HH + i];
    wc4[8L*HH+i] = v; return;
  } i -= HH;
  if (i < kH){ bs[i]        = bias_comb(g1b1, (int)i); return; } i -= kH;
  if (i < kH){ bs[kH+i]     = bias_comb(g1b2, (int)i); return; } i -= kH;
  if (i < kH){ bs[2*kH+i]   = bias_comb(g2b1, (int)i); return; } i -= kH;
  if (i < kH){ bs[3*kH+i]   = bias_comb(g2b2, (int)i); return; } i -= kH;
  if (i < 8L*kN){ cnt[i] = 0; return; } i -= 8L*kN;
  if (i < 4L*kN){ g[i] = -1; return; }
}

// ---------------------------------------------------------------- CSR build (8 lists) + gmax fused
__global__ void edge_cg_kernel(const int* __restrict__ e0, const int* __restrict__ e1,
                               const int* __restrict__ e2, const int* __restrict__ e3,
                               int* __restrict__ cnt, int* __restrict__ g){
  const int* eis[4] = {e0,e1,e2,e3};
  const int e = blockIdx.y;
  const int* ei = eis[e];
  int j = blockIdx.x*256 + threadIdx.x;
  if (j >= kNE) return;
  int s = ei[j], d = ei[kNE + j];
  atomicAdd(&cnt[e*kN + d], 1);
  atomicAdd(&cnt[(4+e)*kN + s], 1);
  atomicMax(&g[e*kN + d], s);
}

// fused: blocks 0-7 = csr exclusive scans (LDS-staged); blocks 8-11 = gmax scan + h binsearch
__global__ __launch_bounds__(256)
void scan12_kernel(const int* __restrict__ cnt, int* __restrict__ offs, int* __restrict__ cur,
                   int* __restrict__ g, int* __restrict__ h){
  __shared__ int buf[kN+1];
  const int b = blockIdx.x, t = threadIdx.x;
  if (b < 8){
    for (int i=t; i<kN; i+=256) buf[i] = cnt[b*kN + i];
    __syncthreads();
    if (t == 0){
      int acc = 0;
      for (int i=0;i<kN;++i){ int c = buf[i]; buf[i] = acc; acc += c; }
      buf[kN] = acc;
    }
    __syncthreads();
    for (int i=t; i<kN; i+=256){ offs[b*(kN+1)+i] = buf[i]; cur[b*kN+i] = buf[i]; }
    if (t == 0) offs[b*(kN+1)+kN] = buf[kN];
  } else {
    const int e = b - 8;
    for (int i=t; i<kN; i+=256) buf[i] = g[e*kN + i];
    __syncthreads();
    if (t == 0){
      int m = -1;
      for (int i=0;i<kN;++i){ m = max(m, buf[i]); buf[i] = m; }
    }
    __syncthreads();
    for (int i=t; i<kN; i+=256) g[e*kN + i] = buf[i];
    for (int d=t; d<kN; d+=256){
      int lo = 0, hi = kN;
      while (lo < hi){ int mid = (lo+hi)>>1; if (buf[mid] >= d) hi = mid; else lo = mid+1; }
      h[e*kN + d] = lo;
    }
  }
}

__global__ void edge_fill_kernel(const int* __restrict__ e0, const int* __restrict__ e1,
                                 const int* __restrict__ e2, const int* __restrict__ e3,
                                 int* __restrict__ cur, int* __restrict__ adj){
  const int* eis[4] = {e0,e1,e2,e3};
  const int e = blockIdx.y;
  const int* ei = eis[e];
  int j = blockIdx.x*256 + threadIdx.x;
  if (j >= kNE) return;
  int s = ei[j], d = ei[kNE + j];
  int p = atomicAdd(&cur[e*kN + d], 1);
  adj[(long)e*kNE + p] = s;
  int q = atomicAdd(&cur[(4+e)*kN + s], 1);
  adj[(long)(4+e)*kNE + q] = d;
}

// CSR gather (sparse): t = Y[8] + bsum + 0.5*msgs; LN stats -> slot (fp64 atomics)
// Adjacency indices are staged into LDS (parallel, one latency) so the per-thread
// Y-row loads have no dependent address chain; 4-way unroll gives MLP=4.
__global__ __launch_bounds__(256)
void gather_sparse_kernel(const float* __restrict__ Y, const int* __restrict__ offs,
                          const int* __restrict__ adj, const float* __restrict__ bsum,
                          float* __restrict__ tnh, double* __restrict__ slot){
  __shared__ double ss[256], qq[256];
  __shared__ int sIdx[256];
  const int n = blockIdx.x;
  const int f = threadIdx.x;
  float acc = 0.f;
  #pragma unroll
  for (int l = 0; l < 8; ++l){
    const float* Yp = Y + (long)l*kNH;
    int b  = offs[l*(kN+1) + n];
    int cnt = offs[l*(kN+1) + n + 1] - b;
    for (int base = 0; base < cnt; base += 256){
      int lim = min(256, cnt - base);
      __syncthreads();
      if (threadIdx.x < lim) sIdx[threadIdx.x] = adj[(long)l*kNE + b + base + threadIdx.x];
      __syncthreads();
      if (f < kH){
        float a0=0.f, a1=0.f, a2=0.f, a3=0.f;
        int i = 0;
        for (; i + 4 <= lim; i += 4){
          a0 += Yp[(long)sIdx[i+0]*kH + f];
          a1 += Yp[(long)sIdx[i+1]*kH + f];
          a2 += Yp[(long)sIdx[i+2]*kH + f];
          a3 += Yp[(long)sIdx[i+3]*kH + f];
        }
        for (; i < lim; ++i) a0 += Yp[(long)sIdx[i]*kH + f];
        acc += (a0 + a1) + (a2 + a3);
      }
    }
  }
  double sp = 0.0, qp = 0.0;
  if (f < kH){
    float t = Y[(long)8*kNH + (long)n*kH + f] + bsum[f] + 0.5f*acc;
    tnh[(long)n*kH + f] = t;
    sp = t; qp = (double)t*t;
  }
  ss[threadIdx.x]=sp; qq[threadIdx.x]=qp;
  __syncthreads();
  for (int hh=128; hh>0; hh>>=1){
    if ((int)threadIdx.x < hh){ ss[threadIdx.x]+=ss[threadIdx.x+hh]; qq[threadIdx.x]+=qq[threadIdx.x+hh]; }
    __syncthreads();
  }
  if (threadIdx.x==0){
    unsafeAtomicAdd(&slot[0], ss[0]);
    unsafeAtomicAdd(&slot[1], qq[0]);
  }
}

// chunked scans over Y planes: z<4 local prefix per chunk; z>=4 local suffix per chunk.
__global__ __launch_bounds__(256)
void scan_chunk_kernel(float* __restrict__ Y, float* __restrict__ Tot){
  const int plane = blockIdx.y;     // 0..7
  const int chunk = blockIdx.x;     // 0..kNCHK-1
  const int f = threadIdx.x;
  if (f >= kH) return;
  float* P = Y + (long)plane*kNH + (long)chunk*kCH*kH + f;
  float acc = 0.f;
  if (plane < 4){
    for (int i0 = 0; i0 < kCH; i0 += 5){
      float v0 = P[(long)(i0+0)*kH], v1 = P[(long)(i0+1)*kH], v2 = P[(long)(i0+2)*kH],
            v3 = P[(long)(i0+3)*kH], v4 = P[(long)(i0+4)*kH];
      acc += v0; P[(long)(i0+0)*kH] = acc;
      acc += v1; P[(long)(i0+1)*kH] = acc;
      acc += v2; P[(long)(i0+2)*kH] = acc;
      acc += v3; P[(long)(i0+3)*kH] = acc;
      acc += v4; P[(long)(i0+4)*kH] = acc;
    }
  } else {
    for (int i0 = kCH-1; i0 >= 4; i0 -= 5){
      float v0 = P[(long)(i0-0)*kH], v1 = P[(long)(i0-1)*kH], v2 = P[(long)(i0-2)*kH],
            v3 = P[(long)(i0-3)*kH], v4 = P[(long)(i0-4)*kH];
      acc += v0; P[(long)(i0-0)*kH] = acc;
      acc += v1; P[(long)(i0-1)*kH] = acc;
      acc += v2; P[(long)(i0-2)*kH] = acc;
      acc += v3; P[(long)(i0-3)*kH] = acc;
      acc += v4; P[(long)(i0-4)*kH] = acc;
    }
  }
  Tot[((long)plane*kNCHK + chunk)*kH + f] = acc;
}

// cross-chunk scan of Tot (in place): planes<4 -> exclusive prefix over chunks;
// planes>=4 -> exclusive suffix. Makes gather_dense O(1) per plane.
__global__ __launch_bounds__(256)
void scan_tot_kernel(float* __restrict__ Tot){
  const int plane = blockIdx.x;
  const int f = threadIdx.x;
  if (f >= kH) return;
  float* T = Tot + (long)plane*kNCHK*kH + f;
  float run = 0.f;
  if (plane < 4){
    for (int c = 0; c < kNCHK; ++c){
      float v = T[(long)c*kH];
      T[(long)c*kH] = run;
      run += v;
    }
  } else {
    for (int c = kNCHK-1; c >= 0; --c){
      float v = T[(long)c*kH];
      T[(long)c*kH] = run;
      run += v;
    }
  }
}

// dense gather: t = Y[8] + bsum + 0.5*(staircase sums); Tot holds exclusive
// prefix/suffix per chunk -> 2 loads per plane. LN stats -> slot (fp64 atomics)
__global__ __launch_bounds__(256)
void gather_dense_kernel(const float* __restrict__ Y, const int* __restrict__ g,
                         const int* __restrict__ h, const float* __restrict__ bsum,
                         const float* __restrict__ Tot,
                         float* __restrict__ tnh, double* __restrict__ slot){
  __shared__ double ss[256], qq[256];
  long idx = (long)blockIdx.x*256 + threadIdx.x;
  double s = 0.0, q = 0.0;
  if (idx < kNH){
    int n = (int)(idx / kH), f = (int)(idx % kH);
    float v = 0.f;
    #pragma unroll
    for (int e = 0; e < 4; ++e){
      int gi = g[e*kN + n];
      if (gi >= 0){
        int cg = (int)((unsigned)gi / (unsigned)kCH);
        v += Y[(long)e*kNH + (long)gi*kH + f] + Tot[((long)e*kNCHK + cg)*kH + f];
      }
      int hi = h[e*kN + n];
      if (hi < kN){
        int ch = (int)((unsigned)hi / (unsigned)kCH);
        v += Y[(long)(4+e)*kNH + (long)hi*kH + f] + Tot[((long)(4+e)*kNCHK + ch)*kH + f];
      }
    }
    float t = Y[(long)8*kNH + idx] + bsum[f] + 0.5f*v;
    tnh[idx] = t;
    s = t; q = (double)t*t;
  }
  ss[threadIdx.x]=s; qq[threadIdx.x]=q;
  __syncthreads();
  for (int hh=128; hh>0; hh>>=1){
    if ((int)threadIdx.x < hh){ ss[threadIdx.x]+=ss[threadIdx.x+hh]; qq[threadIdx.x]+=qq[threadIdx.x+hh]; }
    __syncthreads();
  }
  if (threadIdx.x==0){
    unsafeAtomicAdd(&slot[0], ss[0]);
    unsafeAtomicAdd(&slot[1], qq[0]);
  }
}

// ---- invert the 16 diagonal 50x50 upper-tri blocks of U into W
__global__ __launch_bounds__(64)
void invdiag_kernel(const float* __restrict__ U, float* __restrict__ W){
  __shared__ float Us[kDB][kDB+1];
  __shared__ float Xs[kDB][kDB+1];
  const int base = blockIdx.x * kDB;
  const int tid = threadIdx.x;
  for (int idx = tid; idx < kDB*kDB; idx += 64){
    int r = idx / kDB, c = idx % kDB;
    Us[r][c] = U[(long)(base+r)*kN + base + c];
  }
  __syncthreads();
  const int c = tid;
  for (int i = kDB-1; i >= 0; --i){
    if (c < kDB){
      float x;
      if (c < i) x = 0.f;
      else {
        float s = 0.f;
        for (int k = i+1; k < kDB; ++k) s = fmaf(Us[i][k], Xs[k][c], s);
        x = (((c==i)?1.f:0.f) - s) / Us[i][i];
      }
      Xs[i][c] = x;
    }
    __syncthreads();
  }
  for (int idx = tid; idx < kDB*kDB; idx += 64){
    int r = idx / kDB, cc = idx % kDB;
    W[(long)(base+r)*kN + base + cc] = Xs[r][cc];
  }
}

// ---- fused merge for level S: one block per pair
template<int S>
__global__ __launch_bounds__(256)
void merge_fused_kernel(const float* __restrict__ U, float* __restrict__ W){
  __shared__ float Us[S][S+1];
  __shared__ float Wb[S][S+1];
  __shared__ float T[S][S+1];
  const long base = (long)blockIdx.x * (2*S) * (kN+1);
  const int tid = threadIdx.x;
  for (int idx = tid; idx < S*S; idx += 256){
    int r = idx / S, c = idx % S;
    Us[r][c] = U[base + (long)r*kN + S + c];
    Wb[r][c] = W[base + (long)(S+r)*kN + S + c];
  }
  __syncthreads();
  for (int idx = tid; idx < S*S; idx += 256){
    int r = idx / S, c = idx % S;
    float s = 0.f;
    for (int k = 0; k <= c; ++k) s = fmaf(Us[r][k], Wb[k][c], s);
    T[r][c] = s;
  }
  __syncthreads();
  for (int idx = tid; idx < S*S; idx += 256){
    int r = idx / S, c = idx % S;
    Us[r][c] = W[base + (long)r*kN + c];
  }
  __syncthreads();
  for (int idx = tid; idx < S*S; idx += 256){
    int r = idx / S, c = idx % S;
    float s = 0.f;
    for (int k = r; k < S; ++k) s = fmaf(Us[r][k], T[k][c], s);
    W[base + (long)r*kN + S + c] = -s;
  }
}

// ---- parallel column partial sums of tnh (feeds pool_head; LN commutes with mean)
__global__ __launch_bounds__(256)
void colsum_kernel(const float* __restrict__ tnh, float* __restrict__ colpart){
  const int b = blockIdx.x;          // 0..49, 16 rows each
  const int f = threadIdx.x;
  if (f >= kH) return;
  const float* P = tnh + (long)b*16*kH + f;
  float acc = 0.f;
  #pragma unroll
  for (int i = 0; i < 16; ++i) acc += P[(long)i*kH];
  colpart[(long)b*kH + f] = acc;
}

// pool + classifier + log_softmax, from column partial sums (LN applied to the mean)
__global__ __launch_bounds__(256)
void pool_head_kernel(const float* __restrict__ colpart, const double* __restrict__ lnst,
                      const float* __restrict__ ln,
                      const float* __restrict__ W, const float* __restrict__ b,
                      float* __restrict__ out){
  __shared__ float x2[kH];
  __shared__ float lg[kNC];
  int t = threadIdx.x;
  double m = lnst[0]/(double)kNH;
  const float mu = (float)m;
  const float rs = rsqrtf((float)(lnst[1]/(double)kNH - m*m) + kEps);
  if (t < kH){
    float sum = 0.f;
    for (int bb = 0; bb < 50; ++bb) sum += colpart[(long)bb*kH + t];
    float v = (sum * (1.f/(float)kN) - mu)*(rs*ln[t]) + ln[kH+t];
    x2[t] = v;
    out[t] = v;
  }
  __syncthreads();
  if (t < kNC){
    float sv = b[t];
    for (int f = 0; f < kH; ++f) sv = fmaf(x2[f], W[f*kNC + t], sv);
    lg[t] = sv;
  }
  __syncthreads();
  if (t == 0){
    float m2 = -1e30f;
    for (int c=0;c<kNC;++c) m2 = fmaxf(m2, lg[c]);
    float se = 0.f;
    for (int c=0;c<kNC;++c) se += expf(lg[c]-m2);
    float lse = m2 + logf(se);
    for (int c=0;c<kNC;++c) out[kH + c] = lg[c]-lse;
  }
}

// ---------------------------------------------------------------- host: Pade [5/5] of sqrt(1-x)
static void pade_coeffs(float* P, float* Q){
  double b[11]; b[0] = 1.0;
  for (int k=1;k<11;++k) b[k] = b[k-1]*(0.5-(k-1))/k;
  double c[11];
  for (int k=0;k<11;++k) c[k] = b[k]*((k&1)?-1.0:1.0);
  double A[5][5], rhs[5];
  for (int i=0;i<5;++i){ for (int j=0;j<5;++j) A[i][j] = c[5+i-j]; rhs[i] = -c[6+i]; }
  for (int col=0; col<5; ++col){
    int p = col;
    for (int r=col+1;r<5;++r) if (fabs(A[r][col]) > fabs(A[p][col])) p = r;
    if (p != col){
      for (int j=0;j<5;++j){ double t=A[col][j]; A[col][j]=A[p][j]; A[p][j]=t; }
      double t=rhs[col]; rhs[col]=rhs[p]; rhs[p]=t;
    }
    for (int r=col+1;r<5;++r){
      double f = A[r][col]/A[col][col];
      for (int j=col;j<5;++j) A[r][j] -= f*A[col][j];
      rhs[r] -= f*rhs[col];
    }
  }
  double q[6]; q[0] = 1.0;
  for (int r=4;r>=0;--r){
    double s = rhs[r];
    for (int j=r+1;j<5;++j) s -= A[r][j]*q[1+j];
    q[1+r] = s/A[r][r];
  }
  double p[6];
  for (int k=0;k<6;++k){
    double s = 0.0; int jm = k<5?k:5;
    for (int j=0;j<=jm;++j) s += q[j]*c[k-j];
    p[k] = s;
  }
  for (int k=0;k<6;++k){ P[k]=(float)p[k]; Q[k]=(float)q[k]; }
}

// ---------------------------------------------------------------- launch
extern "C" void kernel_launch(void* const* d_in, const int* in_sizes, int n_in,
                              void* d_out, int out_size, void* d_ws, size_t ws_size,
                              hipStream_t stream)
{
  const float* x_note = (const float*)d_in[0];
  const float* embW   = (const float*)d_in[1];
  const float* embB   = (const float*)d_in[2];
  const float* g1w1   = (const float*)d_in[3];
  const float* g1b1   = (const float*)d_in[4];
  const float* g1w2   = (const float*)d_in[5];
  const float* g1b2   = (const float*)d_in[6];
  const float* g1ln   = (const float*)d_in[7];
  const float* g2w1   = (const float*)d_in[8];
  const float* g2b1   = (const float*)d_in[9];
  const float* g2w2   = (const float*)d_in[10];
  const float* g2b2   = (const float*)d_in[11];
  const float* g2ln   = (const float*)d_in[12];
  const float* linW   = (const float*)d_in[13];
  const float* linb   = (const float*)d_in[14];
  const float* clfW   = (const float*)d_in[15];
  const float* clfb   = (const float*)d_in[16];
  const int*  e0     = (const int*)d_in[17];
  const int*  e1     = (const int*)d_in[18];
  const int*  e2     = (const int*)d_in[19];
  const int*  e3     = (const int*)d_in[20];
  float* out = (float*)d_out;

  // header: scald @0 (frob2 at [3], 6 LN slots at [8..19])
  constexpr long o_h0   = 4096;
  constexpr long o_h1   = o_h0   + (long)kN*kE;
  constexpr long o_h2   = o_h1   + (long)kN*kE;
  constexpr long o_tnh  = o_h2   + (long)kN*kE;
  constexpr long o_pp   = o_tnh  + kNH;             // 4 u16 planes = 2*kNH floats
  constexpr long o_av   = o_pp   + 2*kNH;           // kN floats
  constexpr long o_big  = o_av   + kN;              // 4*kNN floats
  constexpr long o_tri  = o_big  + 4*kNN;
  constexpr long o_sacc = o_tri  + kNN;
  constexpr long o_winv = o_sacc + kNN;
  constexpr long o_psq  = o_winv + kNN;
  constexpr long o_qsq  = o_psq  + kNN;
  constexpr long o_g    = o_qsq  + kNN;
  constexpr long o_hh   = o_g    + 4*kN;
  constexpr long o_wc1  = o_hh   + 4*kN;
  constexpr long o_wc2  = o_wc1  + 9L*kE*kH;
  constexpr long o_wc3  = o_wc2  + 9L*kH*kH;
  constexpr long o_wc4  = o_wc3  + 9L*kE*kH;
  constexpr long o_bs   = o_wc4  + 9L*kH*kH;
  constexpr long o_cnt  = o_bs   + 4*kH;
  constexpr long o_offs = o_cnt  + 8*kN;
  constexpr long o_cur  = o_offs + 8*(kN+1);
  constexpr long o_adj  = o_cur  + 8*kN;
  constexpr long o_end  = o_adj  + 8*(long)kNE;

  if (ws_size < (size_t)o_end*sizeof(float) || out_size < 215 + 2*(int)kNN || n_in < 21){
    fprintf(stderr, "kernel_launch guard: ws=%zu need=%zu out=%d need=%d n_in=%d\n",
            ws_size, (size_t)o_end*sizeof(float), out_size, (int)(215+2*kNN), n_in);
    hipMemsetAsync(d_out, 0, (size_t)out_size*sizeof(float), stream);
    return;
  }

  float* ws = (float*)d_ws;
  double* scald = (double*)d_ws;
  double* slots = scald + 8;   // 6 slots x 2 doubles
  float *h0=ws+o_h0, *h1=ws+o_h1, *h2=ws+o_h2, *tnh=ws+o_tnh,
        *big=ws+o_big, *tri=ws+o_tri, *Sacc=ws+o_sacc, *winv=ws+o_winv,
        *psq=ws+o_psq, *qsq=ws+o_qsq;
  u16* zwh = (u16*)(ws + o_pp);
  u16* zwl = zwh + kNH;
  u16* zzh = zwl + kNH;
  u16* zzl = zzh + kNH;
  float* avec = ws + o_av;
  int* gArr = (int*)(ws + o_g);
  int* hArr = (int*)(ws + o_hh);
  float *wc1=ws+o_wc1, *wc2=ws+o_wc2, *wc3=ws+o_wc3, *wc4=ws+o_wc4, *bs=ws+o_bs;
  int* cntA = (int*)(ws + o_cnt);
  int* offsA= (int*)(ws + o_offs);
  int* curA = (int*)(ws + o_cur);
  int* adjA = (int*)(ws + o_adj);
  u16* papp_h = (u16*)big;
  u16* papp_l = papp_h + kNN;
  u16* pT_h   = papp_l + kNN;
  u16* pT_l   = pT_h + kNN;
  u16* pwA_h  = pT_l + kNN;
  u16* pwA_l  = pwA_h + kNN;
  u16* pwB_h  = pwA_l + kNN;
  u16* pwB_l  = pwB_h + kNN;
  // transient buffers carved from big's slack (big holds 9*kNH Y-planes during layers).
  float* totbuf  = big + (long)9*kNH;                // 8*kNCHK*kH = 25600 floats
  float* colpart = totbuf + (long)8*kNCHK*kH;        // 50*kH = 10000 floats

  float P[6], Q[6];
  pade_coeffs(P, Q);

  auto eg = [](long n){ return dim3((unsigned)((n+255)/256)); };

  // one batch-9 GEMM per layer; lnst!=null -> LN fused into A-load (reads raw tnh)
  auto layer_gemm = [&](const float* hin, int K, const float* wcat,
                        const float* lnp, const double* lnst){
    if (lnst)
      launch_gemm<false,false,EPI_NONE,true>(stream, hin, K, wcat, kH, big, kH,
          kN, kH, K, 9, 0, (long)K*kH, kNH, 0.f, nullptr, 0, nullptr, lnp, lnst);
    else
      launch_gemm<false,false,EPI_NONE>(stream, hin, K, wcat, kH, big, kH,
          kN, kH, K, 9, 0, (long)K*kH, kNH, 0.f);
  };
  auto sparse_layer = [&](const float* hin, int K, const float* wcat, const float* bsum,
                          const float* lnp, const double* lnst, double* slotW){
    layer_gemm(hin, K, wcat, lnp, lnst);
    gather_sparse_kernel<<<dim3(kN),256,0,stream>>>(big, offsA, adjA, bsum, tnh, slotW);
  };
  auto dense_layer = [&](const float* hin, int K, const float* wcat, const float* bsum,
                         const float* lnp, const double* lnst, double* slotW){
    layer_gemm(hin, K, wcat, lnp, lnst);
    scan_chunk_kernel<<<dim3(kNCHK,8),256,0,stream>>>(big, totbuf);
    scan_tot_kernel<<<dim3(8),256,0,stream>>>(totbuf);
    gather_dense_kernel<<<kGB,256,0,stream>>>(big, gArr, hArr, bsum, totbuf, tnh, slotW);
  };
  // NOTE: winv MUST be zeroed per call — the level-400 step and Sacc use EPI_ACC
  // (atomic accumulate), which requires a zeroed destination each invocation.
  // Lesson (R8): keep the K-split GEMM path for s=100/200 — a fused per-pair
  // kernel without register tiling ran 10x slower (serial k-chains + LDS bank
  // conflicts). Low dispatch count loses to per-dispatch efficiency here.
  auto blocked_trsm = [&](){
    hipMemsetAsync(winv, 0, (size_t)kNN*sizeof(float), stream);
    invdiag_kernel<<<dim3(kN/kDB),64,0,stream>>>(qsq, winv);
    merge_fused_kernel<50><<<dim3(kN/100),256,0,stream>>>(qsq, winv);
    {   // level s=100 (4 pairs)
      int s = 100, npairs = 4;
      long step = (long)2*s*kN + 2*s;
      launch_gemm<false,true,EPI_NONE>(stream,
          qsq + s, kN, winv + (long)s*kN + s, kN, tri, s,
          s, s, s, npairs, step, step, (long)s*s, 0.f);
      launch_gemm<true,false,EPI_SCALE>(stream,
          winv, kN, tri, s, winv + s, kN,
          s, s, s, npairs, step, (long)s*s, step, -1.f);
    }
    {   // level s=200 (2 pairs)
      int s = 200, npairs = 2;
      long step = (long)2*s*kN + 2*s;
      launch_gemm<false,true,EPI_NONE>(stream,
          qsq + s, kN, winv + (long)s*kN + s, kN, tri, s,
          s, s, s, npairs, step, step, (long)s*s, 0.f);
      launch_gemm<true,false,EPI_SCALE>(stream,
          winv, kN, tri, s, winv + s, kN,
          s, s, s, npairs, step, (long)s*s, step, -1.f);
    }
    {   // level s=400 (1 pair) — K-split x4, atomic ACC
      hipMemsetAsync(tri, 0, (size_t)400*400*sizeof(float), stream);
      launch_gemm<false,true,EPI_ACC>(stream,
          qsq + 400, kN, winv + (long)400*kN + 400, kN, tri, 400,
          400, 400, 100, 4, 100, (long)100*kN, 0, 1.f, nullptr, 100);
      launch_gemm<true,false,EPI_ACC>(stream,
          winv, kN, tri, 400, winv + 400, kN,
          400, 400, 100, 4, 100, (long)100*400, 0, -1.f, nullptr, 100);
    }
    hipMemsetAsync(Sacc, 0, (size_t)kNN*sizeof(float), stream);
    launch_gemm<true,true,EPI_ACC>(stream,
        winv, kN, psq, kN, Sacc, kN, kN, kN, 100, 8,
        100, (long)100*kN, 0, 1.f, nullptr, 100);
  };
  // consumes raw tnh (LN stats from lnst slot); prep zeroes frob2
  auto run_pair_mpa = [&](const double* lnst, const float* lnp, float* SoutDst){
    ln_pair_prep_kernel<<<dim3(kN),256,0,stream>>>(tnh, lnst, lnp, linW,
                                                   zwh, zwl, zzh, zzl, avec, scald+3);
    bgemm_pair_kernel<<<dim3(13,13),256,0,stream>>>(zwh, zwl, zzh, zzl, avec, linb,
                                                    tri, scald+3);
    pade_both_kernel<<<dim3(25,25),256,0,stream>>>(tri, scald+3, papp_h, papp_l, pT_h, pT_l,
                                                   psq, qsq, P[0],P[1],Q[0],Q[1]);
    dim3 g13(13,13,1);
    bgemm2_kernel<<<g13,256,0,stream>>>(papp_h,papp_l, pT_h,pT_l, psq,qsq, pwA_h,pwA_l, P[2],Q[2]);
    bgemm2_kernel<<<g13,256,0,stream>>>(pwA_h,pwA_l,  pT_h,pT_l, psq,qsq, pwB_h,pwB_l, P[3],Q[3]);
    bgemm2_kernel<<<g13,256,0,stream>>>(pwB_h,pwB_l,  pT_h,pT_l, psq,qsq, pwA_h,pwA_l, P[4],Q[4]);
    bgemm2_kernel<<<g13,256,0,stream>>>(pwA_h,pwA_l,  pT_h,pT_l, psq,qsq, nullptr,nullptr, P[5],Q[5]);
    blocked_trsm();
    copy_scale_kernel<<<eg(kNN),256,0,stream>>>(Sacc, scald+3, SoutDst);
  };
  auto s_times_h = [&](const float* hin, float* hout){
    hipMemsetAsync(hout, 0, (size_t)kN*kE*sizeof(float), stream);
    launch_gemm<true,false,EPI_ACC>(stream,
        Sacc, kN, hin, kE, hout, kE, kN, kE, 100, 8,
        100, (long)100*kE, 0, 1.f, nullptr, 100, scald+3);
  };

  float* S1f = out + 215;
  float* S2f = out + 215 + kNN;

  // ---- setup: fused prep (incl. slot zeroing), CSR build
  {
    constexpr long prep_span = 12 + 2L*(9L*kE*kH + 9L*kH*kH) + 4L*kH + 8L*kN + 4L*kN;
    prep_kernel<<<eg(prep_span),256,0,stream>>>(g1w1, g1b1, g1w2, g1b2,
                                                g2w1, g2b1, g2w2, g2b2,
                                                wc1, wc2, wc3, wc4, bs, cntA, gArr, slots);
  }
  edge_cg_kernel<<<dim3((kNE+255)/256,4),256,0,stream>>>(e0,e1,e2,e3, cntA, gArr);
  scan12_kernel<<<dim3(12),256,0,stream>>>(cntA, offsA, curA, gArr, hArr);
  edge_fill_kernel<<<dim3((kNE+255)/256,4),256,0,stream>>>(e0,e1,e2,e3, curA, adjA);

  // ---- embed (lda=111 -> scalar-load fallback path inside kernel)
  launch_gemm<false,false,EPI_BIAS>(stream, x_note, kF, embW, kE, h0, kE, kN, kE, kF, 1,
                                    0,0,0, 0.f, embB);

  // ---- GNN1 (sparse); layer 2 reads raw tnh with LN fused into GEMM
  sparse_layer(h0,  kE, wc1, bs,      nullptr, nullptr,  slots+0);
  sparse_layer(tnh, kH, wc2, bs+kH,   g1ln,    slots+0,  slots+2);

  // ---- S1 (LN(g1ln[1]) fused into pair prep)
  run_pair_mpa(slots+2, g1ln + 2*kH, S1f);

  // ---- h1 = S1 @ h0
  s_times_h(h0, h1);

  // ---- GNN2 #1 (dense)
  dense_layer(h1,  kE, wc3, bs+2*kH, nullptr, nullptr,  slots+4);
  dense_layer(tnh, kH, wc4, bs+3*kH, g2ln,    slots+4,  slots+6);

  // ---- S2
  run_pair_mpa(slots+6, g2ln + 2*kH, S2f);

  // ---- h2 = S2 @ h1
  s_times_h(h1, h2);

  // ---- GNN2 #2 (dense; mask2 == mask1)
  dense_layer(h2,  kE, wc3, bs+2*kH, nullptr, nullptr,  slots+8);
  dense_layer(tnh, kH, wc4, bs+3*kH, g2ln,    slots+8,  slots+10);

  // ---- pool + classifier + log_softmax (LN fused; pooling via parallel colsums)
  colsum_kernel<<<dim3(50),256,0,stream>>>(tnh, colpart);
  pool_head_kernel<<<dim3(1),256,0,stream>>>(colpart, slots+10, g2ln + 2*kH, clfW, clfb, out);
}